// Round 1
// baseline (1312.698 us; speedup 1.0000x reference)
//
#include <hip/hip_runtime.h>
#include <math.h>

#define HDIM 128
#define ICDIM 64
#define OCDIM 32
#define BN_EPS 1e-5f

// ---------------------------------------------------------------------------
// proj: h = relu(x @ proj_w + proj_b)   x:[n,64] w:[64,128] -> h:[n,128]
// block = 256 threads = 2 nodes x 128 channels
// ---------------------------------------------------------------------------
__global__ void proj_kernel(const float* __restrict__ x,
                            const float* __restrict__ w,
                            const float* __restrict__ b,
                            float* __restrict__ h, int n) {
    __shared__ float xs[2][ICDIM];
    int tid = threadIdx.x;
    if (tid < 2 * ICDIM) {
        int r = tid / ICDIM, c = tid % ICDIM;
        int node = blockIdx.x * 2 + r;
        xs[r][c] = (node < n) ? x[(size_t)node * ICDIM + c] : 0.f;
    }
    __syncthreads();
    int node = blockIdx.x * 2 + (tid >> 7);
    if (node >= n) return;
    int c = tid & 127;
    const float* xr = xs[tid >> 7];
    float acc = b[c];
#pragma unroll
    for (int k = 0; k < ICDIM; ++k)
        acc = fmaf(xr[k], w[k * HDIM + c], acc);
    h[(size_t)node * HDIM + c] = fmaxf(acc, 0.f);
}

// ---------------------------------------------------------------------------
// gemm4: for one layer, compute K,Q,V,S = h @ w[lin] + b[lin], lin = blockIdx.y
// (lin order: key, query, value, skip).  S is also the aggregation buffer.
// block = 256 threads; tile = 64 nodes x 128 cols.
// thread (mg = tid>>5 in 0..7, c = tid&31): rows mg*8..mg*8+7, cols c+{0,32,64,96}
// ---------------------------------------------------------------------------
__global__ void gemm4_kernel(const float* __restrict__ h,
                             const float* __restrict__ w4,   // [4][128][128]
                             const float* __restrict__ b4,   // [4][128]
                             float* __restrict__ ok, float* __restrict__ oq,
                             float* __restrict__ ov, float* __restrict__ os,
                             int n) {
    int lin = blockIdx.y;
    const float* wl = w4 + (size_t)lin * HDIM * HDIM;
    const float* bl = b4 + (size_t)lin * HDIM;
    float* out = (lin == 0) ? ok : (lin == 1) ? oq : (lin == 2) ? ov : os;

    int m0 = blockIdx.x * 64;
    __shared__ float hs[64][HDIM];
    for (int i = threadIdx.x; i < 64 * HDIM; i += 256) {
        int r = i >> 7, c = i & 127;
        int node = m0 + r;
        hs[r][c] = (node < n) ? h[(size_t)node * HDIM + c] : 0.f;
    }
    __syncthreads();

    int c = threadIdx.x & 31;
    int mg = threadIdx.x >> 5;

    float acc[8][4];
#pragma unroll
    for (int i = 0; i < 8; ++i) {
#pragma unroll
        for (int j = 0; j < 4; ++j) acc[i][j] = bl[c + j * 32];
    }

    for (int k = 0; k < HDIM; ++k) {
        float wv0 = wl[k * HDIM + c];
        float wv1 = wl[k * HDIM + c + 32];
        float wv2 = wl[k * HDIM + c + 64];
        float wv3 = wl[k * HDIM + c + 96];
#pragma unroll
        for (int i = 0; i < 8; ++i) {
            float hv = hs[mg * 8 + i][k];
            acc[i][0] = fmaf(hv, wv0, acc[i][0]);
            acc[i][1] = fmaf(hv, wv1, acc[i][1]);
            acc[i][2] = fmaf(hv, wv2, acc[i][2]);
            acc[i][3] = fmaf(hv, wv3, acc[i][3]);
        }
    }

#pragma unroll
    for (int i = 0; i < 8; ++i) {
        int node = m0 + mg * 8 + i;
        if (node < n) {
            float* o = out + (size_t)node * HDIM;
            o[c]      = acc[i][0];
            o[c + 32] = acc[i][1];
            o[c + 64] = acc[i][2];
            o[c + 96] = acc[i][3];
        }
    }
}

// ---------------------------------------------------------------------------
// edge: agg[dst] += sigmoid(k[dst] + q[src]) * v[src]
// block = 256 threads = 2 edges x 128 channels; f32 atomicAdd into S
// ei layout: [src x E | dst x E], int32
// ---------------------------------------------------------------------------
__global__ void edge_kernel(const int* __restrict__ ei,
                            const float* __restrict__ kb,
                            const float* __restrict__ qb,
                            const float* __restrict__ vb,
                            float* __restrict__ agg, int e) {
    __shared__ int sidx[2][2];  // [edge-in-block][0=src,1=dst]
    int tid = threadIdx.x;
    if (tid < 4) {
        int eib = tid >> 1, which = tid & 1;
        int ed = blockIdx.x * 2 + eib;
        sidx[eib][which] = (ed < e) ? ei[(size_t)which * e + ed] : 0;
    }
    __syncthreads();
    int ed = blockIdx.x * 2 + (tid >> 7);
    if (ed >= e) return;
    int c = tid & 127;
    int src = sidx[tid >> 7][0];
    int dst = sidx[tid >> 7][1];
    float g = kb[(size_t)dst * HDIM + c] + qb[(size_t)src * HDIM + c];
    float m = vb[(size_t)src * HDIM + c] / (1.f + __expf(-g));
    atomicAdd(&agg[(size_t)dst * HDIM + c], m);
}

// ---------------------------------------------------------------------------
// stats: per-channel sum and sum-of-squares of S over nodes.
// block = 256 threads covers 128 rows (2 threads per channel).
// ---------------------------------------------------------------------------
__global__ void stats_kernel(const float* __restrict__ s,
                             float* __restrict__ stats, int n) {
    int c = threadIdx.x & 127, rh = threadIdx.x >> 7;
    int r0 = blockIdx.x * 128;
    int r1 = min(r0 + 128, n);
    float sum = 0.f, sq = 0.f;
    for (int r = r0 + rh; r < r1; r += 2) {
        float v = s[(size_t)r * HDIM + c];
        sum += v;
        sq = fmaf(v, v, sq);
    }
    __shared__ float ls[2][HDIM], lq[2][HDIM];
    ls[rh][c] = sum;
    lq[rh][c] = sq;
    __syncthreads();
    if (rh == 0) {
        atomicAdd(&stats[c], ls[0][c] + ls[1][c]);
        atomicAdd(&stats[HDIM + c], lq[0][c] + lq[1][c]);
    }
}

// ---------------------------------------------------------------------------
// bn_relu: h = relu(gamma * (s - mean) * rsqrt(var + eps) + beta)
// scale/shift recomputed per-thread from stats (cheap, cached).
// ---------------------------------------------------------------------------
__global__ void bn_relu_kernel(const float* __restrict__ s,
                               const float* __restrict__ stats,
                               const float* __restrict__ gamma,
                               const float* __restrict__ beta,
                               float* __restrict__ out, int n) {
    size_t idx = (size_t)blockIdx.x * 256 + threadIdx.x;
    size_t total = (size_t)n * HDIM;
    if (idx >= total) return;
    int c = (int)(idx & 127);
    float invn = 1.f / (float)n;
    float mean = stats[c] * invn;
    float var = stats[HDIM + c] * invn - mean * mean;
    float sc = gamma[c] * rsqrtf(var + BN_EPS);
    float sh = beta[c] - mean * sc;
    float v = fmaf(s[idx], sc, sh);
    out[idx] = fmaxf(v, 0.f);
}

// ---------------------------------------------------------------------------
// head: out = h @ head_w + head_b   [n,128] @ [128,32]
// block = 256 threads = 8 nodes x 32 cols, h rows staged in LDS
// ---------------------------------------------------------------------------
__global__ void head_kernel(const float* __restrict__ h,
                            const float* __restrict__ w,
                            const float* __restrict__ b,
                            float* __restrict__ out, int n) {
    __shared__ float hsm[8][HDIM];
    for (int i = threadIdx.x; i < 8 * HDIM; i += 256) {
        int r = i >> 7, c = i & 127;
        int node = blockIdx.x * 8 + r;
        hsm[r][c] = (node < n) ? h[(size_t)node * HDIM + c] : 0.f;
    }
    __syncthreads();
    int c = threadIdx.x & 31;
    int ng = threadIdx.x >> 5;
    int node = blockIdx.x * 8 + ng;
    if (node >= n) return;
    float acc = b[c];
#pragma unroll
    for (int k = 0; k < HDIM; ++k)
        acc = fmaf(hsm[ng][k], w[k * OCDIM + c], acc);
    out[(size_t)node * OCDIM + c] = acc;
}

// ---------------------------------------------------------------------------
extern "C" void kernel_launch(void* const* d_in, const int* in_sizes, int n_in,
                              void* d_out, int out_size, void* d_ws, size_t ws_size,
                              hipStream_t stream) {
    const float* x      = (const float*)d_in[0];
    const int*   ei     = (const int*)  d_in[1];
    const float* proj_w = (const float*)d_in[2];
    const float* proj_b = (const float*)d_in[3];
    const float* conv_w = (const float*)d_in[4];  // [3][4][128][128]
    const float* conv_b = (const float*)d_in[5];  // [3][4][128]
    const float* bn_g   = (const float*)d_in[6];  // [3][128]
    const float* bn_b   = (const float*)d_in[7];  // [3][128]
    const float* head_w = (const float*)d_in[8];  // [128][32]
    const float* head_b = (const float*)d_in[9];  // [32]
    float* out = (float*)d_out;

    int n = in_sizes[0] / ICDIM;   // 50000
    int e = in_sizes[1] / 2;       // 600000

    size_t nh = (size_t)n * HDIM;
    size_t need = (5 * nh + 3 * 256) * sizeof(float);
    if (ws_size < need) return;    // fail loudly (output stays zero)

    float* h   = (float*)d_ws;
    float* K   = h + nh;
    float* Q   = K + nh;
    float* V   = Q + nh;
    float* S   = V + nh;           // skip-proj output == aggregation buffer
    float* st  = S + nh;           // 3 layers x (sum[128], sumsq[128])

    hipMemsetAsync(st, 0, 3 * 256 * sizeof(float), stream);

    // projection
    proj_kernel<<<(n + 1) / 2, 256, 0, stream>>>(x, proj_w, proj_b, h, n);

    int gm = (n + 63) / 64;
    for (int l = 0; l < 3; ++l) {
        const float* wl = conv_w + (size_t)l * 4 * HDIM * HDIM;
        const float* bl = conv_b + (size_t)l * 4 * HDIM;
        gemm4_kernel<<<dim3(gm, 4), 256, 0, stream>>>(h, wl, bl, K, Q, V, S, n);
        edge_kernel<<<(e + 1) / 2, 256, 0, stream>>>(ei, K, Q, V, S, e);
        stats_kernel<<<(n + 127) / 128, 256, 0, stream>>>(S, st + l * 256, n);
        bn_relu_kernel<<<(int)((nh + 255) / 256), 256, 0, stream>>>(
            S, st + l * 256, bn_g + l * HDIM, bn_b + l * HDIM, h, n);
    }

    head_kernel<<<(n + 7) / 8, 256, 0, stream>>>(h, head_w, head_b, out, n);
}

// Round 2
// 1001.102 us; speedup vs baseline: 1.3113x; 1.3113x over previous
//
#include <hip/hip_runtime.h>
#include <math.h>

#define HDIM 128
#define ICDIM 64
#define OCDIM 32
#define BN_EPS 1e-5f

// ---------------------------------------------------------------------------
// proj: h = relu(x @ proj_w + proj_b)   x:[n,64] w:[64,128] -> h:[n,128]
// ---------------------------------------------------------------------------
__global__ void proj_kernel(const float* __restrict__ x,
                            const float* __restrict__ w,
                            const float* __restrict__ b,
                            float* __restrict__ h, int n) {
    __shared__ float xs[2][ICDIM];
    int tid = threadIdx.x;
    if (tid < 2 * ICDIM) {
        int r = tid / ICDIM, c = tid % ICDIM;
        int node = blockIdx.x * 2 + r;
        xs[r][c] = (node < n) ? x[(size_t)node * ICDIM + c] : 0.f;
    }
    __syncthreads();
    int node = blockIdx.x * 2 + (tid >> 7);
    if (node >= n) return;
    int c = tid & 127;
    const float* xr = xs[tid >> 7];
    float acc = b[c];
#pragma unroll
    for (int k = 0; k < ICDIM; ++k)
        acc = fmaf(xr[k], w[k * HDIM + c], acc);
    h[(size_t)node * HDIM + c] = fmaxf(acc, 0.f);
}

// ---------------------------------------------------------------------------
// gemm4: K,Q,V,S = h @ w[lin] + b[lin], lin = blockIdx.y (key,query,value,skip)
// ---------------------------------------------------------------------------
__global__ void gemm4_kernel(const float* __restrict__ h,
                             const float* __restrict__ w4,   // [4][128][128]
                             const float* __restrict__ b4,   // [4][128]
                             float* __restrict__ ok, float* __restrict__ oq,
                             float* __restrict__ ov, float* __restrict__ os,
                             int n) {
    int lin = blockIdx.y;
    const float* wl = w4 + (size_t)lin * HDIM * HDIM;
    const float* bl = b4 + (size_t)lin * HDIM;
    float* out = (lin == 0) ? ok : (lin == 1) ? oq : (lin == 2) ? ov : os;

    int m0 = blockIdx.x * 64;
    __shared__ float hs[64][HDIM];
    for (int i = threadIdx.x; i < 64 * HDIM; i += 256) {
        int r = i >> 7, c = i & 127;
        int node = m0 + r;
        hs[r][c] = (node < n) ? h[(size_t)node * HDIM + c] : 0.f;
    }
    __syncthreads();

    int c = threadIdx.x & 31;
    int mg = threadIdx.x >> 5;

    float acc[8][4];
#pragma unroll
    for (int i = 0; i < 8; ++i) {
#pragma unroll
        for (int j = 0; j < 4; ++j) acc[i][j] = bl[c + j * 32];
    }

    for (int k = 0; k < HDIM; ++k) {
        float wv0 = wl[k * HDIM + c];
        float wv1 = wl[k * HDIM + c + 32];
        float wv2 = wl[k * HDIM + c + 64];
        float wv3 = wl[k * HDIM + c + 96];
#pragma unroll
        for (int i = 0; i < 8; ++i) {
            float hv = hs[mg * 8 + i][k];
            acc[i][0] = fmaf(hv, wv0, acc[i][0]);
            acc[i][1] = fmaf(hv, wv1, acc[i][1]);
            acc[i][2] = fmaf(hv, wv2, acc[i][2]);
            acc[i][3] = fmaf(hv, wv3, acc[i][3]);
        }
    }

#pragma unroll
    for (int i = 0; i < 8; ++i) {
        int node = m0 + mg * 8 + i;
        if (node < n) {
            float* o = out + (size_t)node * HDIM;
            o[c]      = acc[i][0];
            o[c + 32] = acc[i][1];
            o[c + 64] = acc[i][2];
            o[c + 96] = acc[i][3];
        }
    }
}

// ---------------------------------------------------------------------------
// counting sort of edges by dst: hist -> scan(3 kernels) -> scatter
// ---------------------------------------------------------------------------
__global__ void hist_kernel(const int* __restrict__ ei, int* __restrict__ deg, int e) {
    int i = blockIdx.x * 256 + threadIdx.x;
    if (i < e) atomicAdd(&deg[ei[(size_t)e + i]], 1);
}

__global__ void scan1_kernel(const int* __restrict__ deg, int* __restrict__ incl,
                             int* __restrict__ bsum, int n) {
    __shared__ int tmp[256];
    int i = blockIdx.x * 256 + threadIdx.x;
    int v = (i < n) ? deg[i] : 0;
    tmp[threadIdx.x] = v;
    __syncthreads();
    for (int ofs = 1; ofs < 256; ofs <<= 1) {
        int t = (threadIdx.x >= ofs) ? tmp[threadIdx.x - ofs] : 0;
        __syncthreads();
        tmp[threadIdx.x] += t;
        __syncthreads();
    }
    if (i < n) incl[i] = tmp[threadIdx.x];
    if (threadIdx.x == 255) bsum[blockIdx.x] = tmp[255];
}

__global__ void scan2_kernel(int* __restrict__ bsum, int nb) {
    __shared__ int tmp[256];
    int v = (threadIdx.x < nb) ? bsum[threadIdx.x] : 0;
    tmp[threadIdx.x] = v;
    __syncthreads();
    for (int ofs = 1; ofs < 256; ofs <<= 1) {
        int t = (threadIdx.x >= ofs) ? tmp[threadIdx.x - ofs] : 0;
        __syncthreads();
        tmp[threadIdx.x] += t;
        __syncthreads();
    }
    if (threadIdx.x < nb) bsum[threadIdx.x] = tmp[threadIdx.x] - v;  // exclusive
}

__global__ void scan3_kernel(const int* __restrict__ deg, const int* __restrict__ incl,
                             const int* __restrict__ bsum, int* __restrict__ off,
                             int* __restrict__ cursor, int n, int e) {
    int i = blockIdx.x * 256 + threadIdx.x;
    if (i < n) {
        int ex = incl[i] - deg[i] + bsum[blockIdx.x];
        off[i] = ex;
        cursor[i] = ex;
        if (i == n - 1) off[n] = e;
    }
}

__global__ void scatter_kernel(const int* __restrict__ ei, int* __restrict__ cursor,
                               int* __restrict__ esrc, int e) {
    int i = blockIdx.x * 256 + threadIdx.x;
    if (i < e) {
        int dst = ei[(size_t)e + i];
        int pos = atomicAdd(&cursor[dst], 1);
        esrc[pos] = ei[i];
    }
}

// ---------------------------------------------------------------------------
// agg: S[d] += sum_{j in seg(d)} sigmoid(k[d] + q[src_j]) * v[src_j]
// block = 256 threads = 2 dst x 128 channels; register accumulation, no atomics
// ---------------------------------------------------------------------------
__global__ void agg_kernel(const int* __restrict__ off, const int* __restrict__ esrc,
                           const float* __restrict__ kb, const float* __restrict__ qb,
                           const float* __restrict__ vb, float* __restrict__ S, int n) {
    int d = blockIdx.x * 2 + (threadIdx.x >> 7);
    if (d >= n) return;
    int c = threadIdx.x & 127;
    float kv = kb[(size_t)d * HDIM + c];
    float acc = 0.f;
    int s0 = off[d], s1 = off[d + 1];
    for (int j = s0; j < s1; ++j) {
        int src = esrc[j];
        float g = kv + qb[(size_t)src * HDIM + c];
        acc += vb[(size_t)src * HDIM + c] / (1.f + __expf(-g));
    }
    S[(size_t)d * HDIM + c] += acc;
}

// ---------------------------------------------------------------------------
// stats: per-channel sum and sum-of-squares of S over nodes.
// ---------------------------------------------------------------------------
__global__ void stats_kernel(const float* __restrict__ s,
                             float* __restrict__ stats, int n) {
    int c = threadIdx.x & 127, rh = threadIdx.x >> 7;
    int r0 = blockIdx.x * 128;
    int r1 = min(r0 + 128, n);
    float sum = 0.f, sq = 0.f;
    for (int r = r0 + rh; r < r1; r += 2) {
        float v = s[(size_t)r * HDIM + c];
        sum += v;
        sq = fmaf(v, v, sq);
    }
    __shared__ float ls[2][HDIM], lq[2][HDIM];
    ls[rh][c] = sum;
    lq[rh][c] = sq;
    __syncthreads();
    if (rh == 0) {
        atomicAdd(&stats[c], ls[0][c] + ls[1][c]);
        atomicAdd(&stats[HDIM + c], lq[0][c] + lq[1][c]);
    }
}

// ---------------------------------------------------------------------------
// bn_relu: h = relu(gamma * (s - mean) * rsqrt(var + eps) + beta)
// ---------------------------------------------------------------------------
__global__ void bn_relu_kernel(const float* __restrict__ s,
                               const float* __restrict__ stats,
                               const float* __restrict__ gamma,
                               const float* __restrict__ beta,
                               float* __restrict__ out, int n) {
    size_t idx = (size_t)blockIdx.x * 256 + threadIdx.x;
    size_t total = (size_t)n * HDIM;
    if (idx >= total) return;
    int c = (int)(idx & 127);
    float invn = 1.f / (float)n;
    float mean = stats[c] * invn;
    float var = stats[HDIM + c] * invn - mean * mean;
    float sc = gamma[c] * rsqrtf(var + BN_EPS);
    float sh = beta[c] - mean * sc;
    float v = fmaf(s[idx], sc, sh);
    out[idx] = fmaxf(v, 0.f);
}

// ---------------------------------------------------------------------------
// head: out = h @ head_w + head_b   [n,128] @ [128,32]
// ---------------------------------------------------------------------------
__global__ void head_kernel(const float* __restrict__ h,
                            const float* __restrict__ w,
                            const float* __restrict__ b,
                            float* __restrict__ out, int n) {
    __shared__ float hsm[8][HDIM];
    for (int i = threadIdx.x; i < 8 * HDIM; i += 256) {
        int r = i >> 7, c = i & 127;
        int node = blockIdx.x * 8 + r;
        hsm[r][c] = (node < n) ? h[(size_t)node * HDIM + c] : 0.f;
    }
    __syncthreads();
    int c = threadIdx.x & 31;
    int ng = threadIdx.x >> 5;
    int node = blockIdx.x * 8 + ng;
    if (node >= n) return;
    float acc = b[c];
#pragma unroll
    for (int k = 0; k < HDIM; ++k)
        acc = fmaf(hsm[ng][k], w[k * OCDIM + c], acc);
    out[(size_t)node * OCDIM + c] = acc;
}

// ---------------------------------------------------------------------------
extern "C" void kernel_launch(void* const* d_in, const int* in_sizes, int n_in,
                              void* d_out, int out_size, void* d_ws, size_t ws_size,
                              hipStream_t stream) {
    const float* x      = (const float*)d_in[0];
    const int*   ei     = (const int*)  d_in[1];
    const float* proj_w = (const float*)d_in[2];
    const float* proj_b = (const float*)d_in[3];
    const float* conv_w = (const float*)d_in[4];  // [3][4][128][128]
    const float* conv_b = (const float*)d_in[5];  // [3][4][128]
    const float* bn_g   = (const float*)d_in[6];  // [3][128]
    const float* bn_b   = (const float*)d_in[7];  // [3][128]
    const float* head_w = (const float*)d_in[8];  // [128][32]
    const float* head_b = (const float*)d_in[9];  // [32]
    float* out = (float*)d_out;

    int n = in_sizes[0] / ICDIM;   // 50000
    int e = in_sizes[1] / 2;       // 600000

    size_t nh = (size_t)n * HDIM;
    // float region: h,K,Q,V,S (5*nh) + st (3*256)
    // int region: deg[n], incl[n], off[n+1], cursor[n], bsum[256], esrc[e]
    size_t fl = 5 * nh + 3 * 256;
    size_t il = (size_t)3 * n + (n + 1) + 256 + e;
    size_t need = fl * sizeof(float) + il * sizeof(int);
    if (ws_size < need) return;

    float* h   = (float*)d_ws;
    float* K   = h + nh;
    float* Q   = K + nh;
    float* V   = Q + nh;
    float* S   = V + nh;
    float* st  = S + nh;           // 3 layers x (sum[128], sumsq[128])

    int* deg    = (int*)(st + 3 * 256);
    int* incl   = deg + n;
    int* off    = incl + n;        // n+1
    int* cursor = off + n + 1;
    int* bsum   = cursor + n;      // 256
    int* esrc   = bsum + 256;      // e

    hipMemsetAsync(st, 0, 3 * 256 * sizeof(float), stream);
    hipMemsetAsync(deg, 0, (size_t)n * sizeof(int), stream);

    int gb_e = (e + 255) / 256;
    int gb_n = (n + 255) / 256;   // 196 blocks; scan2 handles up to 256

    proj_kernel<<<(n + 1) / 2, 256, 0, stream>>>(x, proj_w, proj_b, h, n);

    // counting sort by dst (edge list is static; recomputed each call for determinism)
    hist_kernel<<<gb_e, 256, 0, stream>>>(ei, deg, e);
    scan1_kernel<<<gb_n, 256, 0, stream>>>(deg, incl, bsum, n);
    scan2_kernel<<<1, 256, 0, stream>>>(bsum, gb_n);
    scan3_kernel<<<gb_n, 256, 0, stream>>>(deg, incl, bsum, off, cursor, n, e);
    scatter_kernel<<<gb_e, 256, 0, stream>>>(ei, cursor, esrc, e);

    int gm = (n + 63) / 64;
    for (int l = 0; l < 3; ++l) {
        const float* wl = conv_w + (size_t)l * 4 * HDIM * HDIM;
        const float* bl = conv_b + (size_t)l * 4 * HDIM;
        gemm4_kernel<<<dim3(gm, 4), 256, 0, stream>>>(h, wl, bl, K, Q, V, S, n);
        agg_kernel<<<(n + 1) / 2, 256, 0, stream>>>(off, esrc, K, Q, V, S, n);
        stats_kernel<<<(n + 127) / 128, 256, 0, stream>>>(S, st + l * 256, n);
        bn_relu_kernel<<<(int)((nh + 255) / 256), 256, 0, stream>>>(
            S, st + l * 256, bn_g + l * HDIM, bn_b + l * HDIM, h, n);
    }

    head_kernel<<<(n + 7) / 8, 256, 0, stream>>>(h, head_w, head_b, out, n);
}

// Round 3
// 888.620 us; speedup vs baseline: 1.4772x; 1.1266x over previous
//
#include <hip/hip_runtime.h>
#include <hip/hip_bf16.h>
#include <math.h>

#define HDIM 128
#define ICDIM 64
#define OCDIM 32
#define BN_EPS 1e-5f

typedef __attribute__((ext_vector_type(8))) short bv8;   // 8 x bf16 bits (4 VGPR)
typedef __attribute__((ext_vector_type(4))) float fv4;   // MFMA accumulator

static __device__ __forceinline__ unsigned short f2bf(float v) {
    __hip_bfloat16 t = __float2bfloat16(v);
    return *(unsigned short*)&t;
}

// ---------------------------------------------------------------------------
// proj: h = relu(x @ proj_w + proj_b)  -> bf16 h
// ---------------------------------------------------------------------------
__global__ void proj_kernel(const float* __restrict__ x,
                            const float* __restrict__ w,
                            const float* __restrict__ b,
                            __hip_bfloat16* __restrict__ h, int n) {
    __shared__ float xs[2][ICDIM];
    int tid = threadIdx.x;
    if (tid < 2 * ICDIM) {
        int r = tid / ICDIM, c = tid % ICDIM;
        int node = blockIdx.x * 2 + r;
        xs[r][c] = (node < n) ? x[(size_t)node * ICDIM + c] : 0.f;
    }
    __syncthreads();
    int node = blockIdx.x * 2 + (tid >> 7);
    if (node >= n) return;
    int c = tid & 127;
    const float* xr = xs[tid >> 7];
    float acc = b[c];
#pragma unroll
    for (int k = 0; k < ICDIM; ++k)
        acc = fmaf(xr[k], w[k * HDIM + c], acc);
    h[(size_t)node * HDIM + c] = __float2bfloat16(fmaxf(acc, 0.f));
}

// ---------------------------------------------------------------------------
// wconv: conv_w [12][128in][128out] f32  ->  Wt [12][128out][128in] bf16
// ---------------------------------------------------------------------------
__global__ void wconv_kernel(const float* __restrict__ src,
                             __hip_bfloat16* __restrict__ dst) {
    int mat = blockIdx.x;  // 0..11
    const float* s = src + (size_t)mat * HDIM * HDIM;
    __hip_bfloat16* d = dst + (size_t)mat * HDIM * HDIM;
    for (int idx = threadIdx.x; idx < HDIM * HDIM; idx += 256) {
        int i = idx >> 7, o = idx & 127;          // coalesced read
        d[(size_t)o * HDIM + i] = __float2bfloat16(s[idx]);
    }
}

// ---------------------------------------------------------------------------
// gemm4_mfma: per layer, O = h @ W[lin] + b[lin] for lin = blockIdx.y
//   computed as D = Wt-frag (A) x h-frag (B)  ->  D row = out-ch, col = node.
//   block = 256 thr = 4 waves; wave w owns 16 nodes; 8 ch-groups x 4 K-steps.
//   lin 0,1,2 -> bf16 K,Q,V ; lin 3 -> f32 S (skip, doubles as agg buffer).
// ---------------------------------------------------------------------------
__global__ void gemm4_mfma_kernel(const __hip_bfloat16* __restrict__ h,
                                  const __hip_bfloat16* __restrict__ wt4, // [4][128o][128i]
                                  const float* __restrict__ b4,           // [4][128]
                                  __hip_bfloat16* __restrict__ K,
                                  __hip_bfloat16* __restrict__ Q,
                                  __hip_bfloat16* __restrict__ V,
                                  float* __restrict__ S, int n) {
    int lin = blockIdx.y;
    const unsigned short* w = (const unsigned short*)(wt4 + (size_t)lin * HDIM * HDIM);
    const float* bl = b4 + lin * HDIM;

    int lane = threadIdx.x & 63;
    int wv = threadIdx.x >> 6;
    int j = lane & 15;            // node within 16 (B col, D col)
    int kg = lane >> 4;           // 0..3 k-group
    int node = blockIdx.x * 64 + wv * 16 + j;
    bool valid = node < n;

    fv4 acc[8];
#pragma unroll
    for (int g = 0; g < 8; ++g) acc[g] = (fv4){0.f, 0.f, 0.f, 0.f};

    const unsigned short* hrow =
        (const unsigned short*)(h + (size_t)(valid ? node : 0) * HDIM) + kg * 8;
#pragma unroll
    for (int ks = 0; ks < 4; ++ks) {
        bv8 bfrag = *(const bv8*)(hrow + ks * 32);
#pragma unroll
        for (int g = 0; g < 8; ++g) {
            bv8 afrag = *(const bv8*)(w + (size_t)(g * 16 + j) * HDIM + ks * 32 + kg * 8);
            acc[g] = __builtin_amdgcn_mfma_f32_16x16x32_bf16(afrag, bfrag, acc[g], 0, 0, 0);
        }
    }
    if (!valid) return;

    int cb = kg * 4;  // this lane holds channels g*16+cb .. +3 for its node
    if (lin == 3) {
        float* o = S + (size_t)node * HDIM;
#pragma unroll
        for (int g = 0; g < 8; ++g) {
            float4 bb = *(const float4*)(bl + g * 16 + cb);
            float4 r;
            r.x = acc[g].x + bb.x; r.y = acc[g].y + bb.y;
            r.z = acc[g].z + bb.z; r.w = acc[g].w + bb.w;
            *(float4*)(o + g * 16 + cb) = r;
        }
    } else {
        __hip_bfloat16* ob = (lin == 0) ? K : (lin == 1) ? Q : V;
        unsigned short* o = (unsigned short*)(ob + (size_t)node * HDIM);
#pragma unroll
        for (int g = 0; g < 8; ++g) {
            float4 bb = *(const float4*)(bl + g * 16 + cb);
            ushort4 r;
            r.x = f2bf(acc[g].x + bb.x); r.y = f2bf(acc[g].y + bb.y);
            r.z = f2bf(acc[g].z + bb.z); r.w = f2bf(acc[g].w + bb.w);
            *(ushort4*)(o + g * 16 + cb) = r;
        }
    }
}

// ---------------------------------------------------------------------------
// counting sort of edges by dst: hist -> scan(3 kernels) -> scatter
// ---------------------------------------------------------------------------
__global__ void hist_kernel(const int* __restrict__ ei, int* __restrict__ deg, int e) {
    int i = blockIdx.x * 256 + threadIdx.x;
    if (i < e) atomicAdd(&deg[ei[(size_t)e + i]], 1);
}

__global__ void scan1_kernel(const int* __restrict__ deg, int* __restrict__ incl,
                             int* __restrict__ bsum, int n) {
    __shared__ int tmp[256];
    int i = blockIdx.x * 256 + threadIdx.x;
    int v = (i < n) ? deg[i] : 0;
    tmp[threadIdx.x] = v;
    __syncthreads();
    for (int ofs = 1; ofs < 256; ofs <<= 1) {
        int t = (threadIdx.x >= ofs) ? tmp[threadIdx.x - ofs] : 0;
        __syncthreads();
        tmp[threadIdx.x] += t;
        __syncthreads();
    }
    if (i < n) incl[i] = tmp[threadIdx.x];
    if (threadIdx.x == 255) bsum[blockIdx.x] = tmp[255];
}

__global__ void scan2_kernel(int* __restrict__ bsum, int nb) {
    __shared__ int tmp[256];
    int v = (threadIdx.x < nb) ? bsum[threadIdx.x] : 0;
    tmp[threadIdx.x] = v;
    __syncthreads();
    for (int ofs = 1; ofs < 256; ofs <<= 1) {
        int t = (threadIdx.x >= ofs) ? tmp[threadIdx.x - ofs] : 0;
        __syncthreads();
        tmp[threadIdx.x] += t;
        __syncthreads();
    }
    if (threadIdx.x < nb) bsum[threadIdx.x] = tmp[threadIdx.x] - v;  // exclusive
}

__global__ void scan3_kernel(const int* __restrict__ deg, const int* __restrict__ incl,
                             const int* __restrict__ bsum, int* __restrict__ off,
                             int* __restrict__ cursor, int n, int e) {
    int i = blockIdx.x * 256 + threadIdx.x;
    if (i < n) {
        int ex = incl[i] - deg[i] + bsum[blockIdx.x];
        off[i] = ex;
        cursor[i] = ex;
        if (i == n - 1) off[n] = e;
    }
}

__global__ void scatter_kernel(const int* __restrict__ ei, int* __restrict__ cursor,
                               int* __restrict__ esrc, int e) {
    int i = blockIdx.x * 256 + threadIdx.x;
    if (i < e) {
        int dst = ei[(size_t)e + i];
        int pos = atomicAdd(&cursor[dst], 1);
        esrc[pos] = ei[i];
    }
}

// ---------------------------------------------------------------------------
// agg: S[d] += sum_{j in seg(d)} sigmoid(k[d] + q[src_j]) * v[src_j]
// bf16 gathers, f32 accumulate, no atomics
// ---------------------------------------------------------------------------
__global__ void agg_kernel(const int* __restrict__ off, const int* __restrict__ esrc,
                           const __hip_bfloat16* __restrict__ kb,
                           const __hip_bfloat16* __restrict__ qb,
                           const __hip_bfloat16* __restrict__ vb,
                           float* __restrict__ S, int n) {
    int d = blockIdx.x * 2 + (threadIdx.x >> 7);
    if (d >= n) return;
    int c = threadIdx.x & 127;
    float kv = __bfloat162float(kb[(size_t)d * HDIM + c]);
    float acc = 0.f;
    int s1 = off[d + 1];
    for (int jj = off[d]; jj < s1; ++jj) {
        int src = esrc[jj];
        float g = kv + __bfloat162float(qb[(size_t)src * HDIM + c]);
        float v = __bfloat162float(vb[(size_t)src * HDIM + c]);
        acc += v * __fdividef(1.f, 1.f + __expf(-g));
    }
    S[(size_t)d * HDIM + c] += acc;
}

// ---------------------------------------------------------------------------
// stats: per-channel sum / sumsq of S
// ---------------------------------------------------------------------------
__global__ void stats_kernel(const float* __restrict__ s,
                             float* __restrict__ stats, int n) {
    int c = threadIdx.x & 127, rh = threadIdx.x >> 7;
    int r0 = blockIdx.x * 128;
    int r1 = min(r0 + 128, n);
    float sum = 0.f, sq = 0.f;
    for (int r = r0 + rh; r < r1; r += 2) {
        float v = s[(size_t)r * HDIM + c];
        sum += v;
        sq = fmaf(v, v, sq);
    }
    __shared__ float ls[2][HDIM], lq[2][HDIM];
    ls[rh][c] = sum;
    lq[rh][c] = sq;
    __syncthreads();
    if (rh == 0) {
        atomicAdd(&stats[c], ls[0][c] + ls[1][c]);
        atomicAdd(&stats[HDIM + c], lq[0][c] + lq[1][c]);
    }
}

// ---------------------------------------------------------------------------
// bn_relu: h = relu(gamma * (s - mean) * rsqrt(var + eps) + beta) -> bf16 h
// ---------------------------------------------------------------------------
__global__ void bn_relu_kernel(const float* __restrict__ s,
                               const float* __restrict__ stats,
                               const float* __restrict__ gamma,
                               const float* __restrict__ beta,
                               __hip_bfloat16* __restrict__ out, int n) {
    size_t idx = (size_t)blockIdx.x * 256 + threadIdx.x;
    size_t total = (size_t)n * HDIM;
    if (idx >= total) return;
    int c = (int)(idx & 127);
    float invn = 1.f / (float)n;
    float mean = stats[c] * invn;
    float var = stats[HDIM + c] * invn - mean * mean;
    float sc = gamma[c] * rsqrtf(var + BN_EPS);
    float sh = beta[c] - mean * sc;
    float v = fmaf(s[idx], sc, sh);
    out[idx] = __float2bfloat16(fmaxf(v, 0.f));
}

// ---------------------------------------------------------------------------
// head: out = h @ head_w + head_b   [n,128] @ [128,32], h is bf16
// ---------------------------------------------------------------------------
__global__ void head_kernel(const __hip_bfloat16* __restrict__ h,
                            const float* __restrict__ w,
                            const float* __restrict__ b,
                            float* __restrict__ out, int n) {
    __shared__ float hsm[8][HDIM];
    for (int i = threadIdx.x; i < 8 * HDIM; i += 256) {
        int r = i >> 7, c = i & 127;
        int node = blockIdx.x * 8 + r;
        hsm[r][c] = (node < n) ? __bfloat162float(h[(size_t)node * HDIM + c]) : 0.f;
    }
    __syncthreads();
    int c = threadIdx.x & 31;
    int ng = threadIdx.x >> 5;
    int node = blockIdx.x * 8 + ng;
    if (node >= n) return;
    float acc = b[c];
#pragma unroll
    for (int k = 0; k < HDIM; ++k)
        acc = fmaf(hsm[ng][k], w[k * OCDIM + c], acc);
    out[(size_t)node * OCDIM + c] = acc;
}

// ---------------------------------------------------------------------------
extern "C" void kernel_launch(void* const* d_in, const int* in_sizes, int n_in,
                              void* d_out, int out_size, void* d_ws, size_t ws_size,
                              hipStream_t stream) {
    const float* x      = (const float*)d_in[0];
    const int*   ei     = (const int*)  d_in[1];
    const float* proj_w = (const float*)d_in[2];
    const float* proj_b = (const float*)d_in[3];
    const float* conv_w = (const float*)d_in[4];  // [3][4][128][128]
    const float* conv_b = (const float*)d_in[5];  // [3][4][128]
    const float* bn_g   = (const float*)d_in[6];
    const float* bn_b   = (const float*)d_in[7];
    const float* head_w = (const float*)d_in[8];
    const float* head_b = (const float*)d_in[9];
    float* out = (float*)d_out;

    int n = in_sizes[0] / ICDIM;   // 50000
    int e = in_sizes[1] / 2;       // 600000

    size_t nh = (size_t)n * HDIM;
    // layout: S f32 | st f32[768] | h,K,Q,V bf16 | Wt bf16[12*16384] | ints
    size_t need = nh * 4 + 768 * 4 + 4 * nh * 2 + (size_t)12 * HDIM * HDIM * 2
                + ((size_t)3 * n + (n + 1) + 256 + e) * 4;
    if (ws_size < need) return;

    float* S  = (float*)d_ws;
    float* st = S + nh;                         // 3 x (sum[128], sumsq[128])
    __hip_bfloat16* h = (__hip_bfloat16*)(st + 768);
    __hip_bfloat16* K = h + nh;
    __hip_bfloat16* Q = K + nh;
    __hip_bfloat16* V = Q + nh;
    __hip_bfloat16* Wt = V + nh;                // [3][4][128out][128in]

    int* deg    = (int*)(Wt + (size_t)12 * HDIM * HDIM);
    int* incl   = deg + n;
    int* off    = incl + n;                     // n+1
    int* cursor = off + n + 1;
    int* bsum   = cursor + n;                   // 256
    int* esrc   = bsum + 256;                   // e

    hipMemsetAsync(st, 0, 768 * sizeof(float), stream);
    hipMemsetAsync(deg, 0, (size_t)n * sizeof(int), stream);

    int gb_e = (e + 255) / 256;
    int gb_n = (n + 255) / 256;   // 196 <= 256, scan2 ok

    proj_kernel<<<(n + 1) / 2, 256, 0, stream>>>(x, proj_w, proj_b, h, n);
    wconv_kernel<<<12, 256, 0, stream>>>(conv_w, Wt);

    hist_kernel<<<gb_e, 256, 0, stream>>>(ei, deg, e);
    scan1_kernel<<<gb_n, 256, 0, stream>>>(deg, incl, bsum, n);
    scan2_kernel<<<1, 256, 0, stream>>>(bsum, gb_n);
    scan3_kernel<<<gb_n, 256, 0, stream>>>(deg, incl, bsum, off, cursor, n, e);
    scatter_kernel<<<gb_e, 256, 0, stream>>>(ei, cursor, esrc, e);

    int gm = (n + 63) / 64;
    for (int l = 0; l < 3; ++l) {
        gemm4_mfma_kernel<<<dim3(gm, 4), 256, 0, stream>>>(
            h, Wt + (size_t)l * 4 * HDIM * HDIM, conv_b + (size_t)l * 4 * HDIM,
            K, Q, V, S, n);
        agg_kernel<<<(n + 1) / 2, 256, 0, stream>>>(off, esrc, K, Q, V, S, n);
        stats_kernel<<<(n + 127) / 128, 256, 0, stream>>>(S, st + l * 256, n);
        bn_relu_kernel<<<(int)((nh + 255) / 256), 256, 0, stream>>>(
            S, st + l * 256, bn_g + l * HDIM, bn_b + l * HDIM, h, n);
    }

    head_kernel<<<(n + 7) / 8, 256, 0, stream>>>(h, head_w, head_b, out, n);
}

// Round 4
// 637.309 us; speedup vs baseline: 2.0598x; 1.3943x over previous
//
#include <hip/hip_runtime.h>
#include <hip/hip_bf16.h>
#include <math.h>

#define HDIM 128
#define ICDIM 64
#define OCDIM 32
#define BN_EPS 1e-5f

typedef __attribute__((ext_vector_type(8))) short bv8;   // 8 x bf16 bits (4 VGPR)
typedef __attribute__((ext_vector_type(4))) float fv4;   // MFMA accumulator

static __device__ __forceinline__ unsigned short f2bf(float v) {
    __hip_bfloat16 t = __float2bfloat16(v);
    return *(unsigned short*)&t;
}
static __device__ __forceinline__ float bflo(unsigned int u) {
    union { unsigned int i; float f; } c; c.i = u << 16; return c.f;
}
static __device__ __forceinline__ float bfhi(unsigned int u) {
    union { unsigned int i; float f; } c; c.i = u & 0xffff0000u; return c.f;
}

// ---------------------------------------------------------------------------
// proj: h = relu(x @ proj_w + proj_b)  -> bf16 h
// ---------------------------------------------------------------------------
__global__ void proj_kernel(const float* __restrict__ x,
                            const float* __restrict__ w,
                            const float* __restrict__ b,
                            __hip_bfloat16* __restrict__ h, int n) {
    __shared__ float xs[2][ICDIM];
    int tid = threadIdx.x;
    if (tid < 2 * ICDIM) {
        int r = tid / ICDIM, c = tid % ICDIM;
        int node = blockIdx.x * 2 + r;
        xs[r][c] = (node < n) ? x[(size_t)node * ICDIM + c] : 0.f;
    }
    __syncthreads();
    int node = blockIdx.x * 2 + (tid >> 7);
    if (node >= n) return;
    int c = tid & 127;
    const float* xr = xs[tid >> 7];
    float acc = b[c];
#pragma unroll
    for (int k = 0; k < ICDIM; ++k)
        acc = fmaf(xr[k], w[k * HDIM + c], acc);
    h[(size_t)node * HDIM + c] = __float2bfloat16(fmaxf(acc, 0.f));
}

// ---------------------------------------------------------------------------
// wconv: conv_w [12][128in][128out] f32  ->  Wt [12][128out][128in] bf16
// ---------------------------------------------------------------------------
__global__ void wconv_kernel(const float* __restrict__ src,
                             __hip_bfloat16* __restrict__ dst) {
    int mat = blockIdx.x;  // 0..11
    const float* s = src + (size_t)mat * HDIM * HDIM;
    __hip_bfloat16* d = dst + (size_t)mat * HDIM * HDIM;
    for (int idx = threadIdx.x; idx < HDIM * HDIM; idx += 256) {
        int i = idx >> 7, o = idx & 127;          // coalesced read
        d[(size_t)o * HDIM + i] = __float2bfloat16(s[idx]);
    }
}

// ---------------------------------------------------------------------------
// gemm4_mfma: per layer, O = h @ W[lin] + b[lin] for lin = blockIdx.y
//   D = Wt-frag (A) x h-frag (B) -> D row = out-ch, col = node.
// ---------------------------------------------------------------------------
__global__ void gemm4_mfma_kernel(const __hip_bfloat16* __restrict__ h,
                                  const __hip_bfloat16* __restrict__ wt4, // [4][128o][128i]
                                  const float* __restrict__ b4,           // [4][128]
                                  __hip_bfloat16* __restrict__ K,
                                  __hip_bfloat16* __restrict__ Q,
                                  __hip_bfloat16* __restrict__ V,
                                  float* __restrict__ S, int n) {
    int lin = blockIdx.y;
    const unsigned short* w = (const unsigned short*)(wt4 + (size_t)lin * HDIM * HDIM);
    const float* bl = b4 + lin * HDIM;

    int lane = threadIdx.x & 63;
    int wv = threadIdx.x >> 6;
    int j = lane & 15;            // node within 16 (B col, D col)
    int kg = lane >> 4;           // 0..3 k-group
    int node = blockIdx.x * 64 + wv * 16 + j;
    bool valid = node < n;

    fv4 acc[8];
#pragma unroll
    for (int g = 0; g < 8; ++g) acc[g] = (fv4){0.f, 0.f, 0.f, 0.f};

    const unsigned short* hrow =
        (const unsigned short*)(h + (size_t)(valid ? node : 0) * HDIM) + kg * 8;
#pragma unroll
    for (int ks = 0; ks < 4; ++ks) {
        bv8 bfrag = *(const bv8*)(hrow + ks * 32);
#pragma unroll
        for (int g = 0; g < 8; ++g) {
            bv8 afrag = *(const bv8*)(w + (size_t)(g * 16 + j) * HDIM + ks * 32 + kg * 8);
            acc[g] = __builtin_amdgcn_mfma_f32_16x16x32_bf16(afrag, bfrag, acc[g], 0, 0, 0);
        }
    }
    if (!valid) return;

    int cb = kg * 4;  // this lane holds channels g*16+cb .. +3 for its node
    if (lin == 3) {
        float* o = S + (size_t)node * HDIM;
#pragma unroll
        for (int g = 0; g < 8; ++g) {
            float4 bb = *(const float4*)(bl + g * 16 + cb);
            float4 r;
            r.x = acc[g].x + bb.x; r.y = acc[g].y + bb.y;
            r.z = acc[g].z + bb.z; r.w = acc[g].w + bb.w;
            *(float4*)(o + g * 16 + cb) = r;
        }
    } else {
        __hip_bfloat16* ob = (lin == 0) ? K : (lin == 1) ? Q : V;
        unsigned short* o = (unsigned short*)(ob + (size_t)node * HDIM);
#pragma unroll
        for (int g = 0; g < 8; ++g) {
            float4 bb = *(const float4*)(bl + g * 16 + cb);
            ushort4 r;
            r.x = f2bf(acc[g].x + bb.x); r.y = f2bf(acc[g].y + bb.y);
            r.z = f2bf(acc[g].z + bb.z); r.w = f2bf(acc[g].w + bb.w);
            *(ushort4*)(o + g * 16 + cb) = r;
        }
    }
}

// ---------------------------------------------------------------------------
// counting sort of edges by dst: hist -> scan(3 kernels) -> scatter
// ---------------------------------------------------------------------------
__global__ void hist_kernel(const int* __restrict__ ei, int* __restrict__ deg, int e) {
    int i = blockIdx.x * 256 + threadIdx.x;
    if (i < e) atomicAdd(&deg[ei[(size_t)e + i]], 1);
}

__global__ void scan1_kernel(const int* __restrict__ deg, int* __restrict__ incl,
                             int* __restrict__ bsum, int n) {
    __shared__ int tmp[256];
    int i = blockIdx.x * 256 + threadIdx.x;
    int v = (i < n) ? deg[i] : 0;
    tmp[threadIdx.x] = v;
    __syncthreads();
    for (int ofs = 1; ofs < 256; ofs <<= 1) {
        int t = (threadIdx.x >= ofs) ? tmp[threadIdx.x - ofs] : 0;
        __syncthreads();
        tmp[threadIdx.x] += t;
        __syncthreads();
    }
    if (i < n) incl[i] = tmp[threadIdx.x];
    if (threadIdx.x == 255) bsum[blockIdx.x] = tmp[255];
}

__global__ void scan2_kernel(int* __restrict__ bsum, int nb) {
    __shared__ int tmp[256];
    int v = (threadIdx.x < nb) ? bsum[threadIdx.x] : 0;
    tmp[threadIdx.x] = v;
    __syncthreads();
    for (int ofs = 1; ofs < 256; ofs <<= 1) {
        int t = (threadIdx.x >= ofs) ? tmp[threadIdx.x - ofs] : 0;
        __syncthreads();
        tmp[threadIdx.x] += t;
        __syncthreads();
    }
    if (threadIdx.x < nb) bsum[threadIdx.x] = tmp[threadIdx.x] - v;  // exclusive
}

__global__ void scan3_kernel(const int* __restrict__ deg, const int* __restrict__ incl,
                             const int* __restrict__ bsum, int* __restrict__ off,
                             int* __restrict__ cursor, int n, int e) {
    int i = blockIdx.x * 256 + threadIdx.x;
    if (i < n) {
        int ex = incl[i] - deg[i] + bsum[blockIdx.x];
        off[i] = ex;
        cursor[i] = ex;
        if (i == n - 1) off[n] = e;
    }
}

__global__ void scatter_kernel(const int* __restrict__ ei, int* __restrict__ cursor,
                               int* __restrict__ esrc, int e) {
    int i = blockIdx.x * 256 + threadIdx.x;
    if (i < e) {
        int dst = ei[(size_t)e + i];
        int pos = atomicAdd(&cursor[dst], 1);
        esrc[pos] = ei[i];
    }
}

// ---------------------------------------------------------------------------
// agg: S[d] += sum_{j in seg(d)} sigmoid(k[d] + q[src_j]) * v[src_j]
// one wave per dst, 2 channels per lane (bf16x2), unroll x4 with prefetch
// ---------------------------------------------------------------------------
__global__ void agg_kernel(const int* __restrict__ off, const int* __restrict__ esrc,
                           const __hip_bfloat16* __restrict__ kb,
                           const __hip_bfloat16* __restrict__ qb,
                           const __hip_bfloat16* __restrict__ vb,
                           float* __restrict__ S, int n) {
    int d = blockIdx.x * 4 + (threadIdx.x >> 6);
    if (d >= n) return;
    int lane = threadIdx.x & 63;
    const unsigned int* qw = (const unsigned int*)qb;   // [node][64] words
    const unsigned int* vw = (const unsigned int*)vb;
    unsigned int kwu = ((const unsigned int*)kb)[(size_t)d * 64 + lane];
    float k0 = bflo(kwu), k1 = bfhi(kwu);
    float a0 = 0.f, a1 = 0.f;

#define EDGE(qu, vu)                                          \
    {                                                         \
        float g0 = k0 + bflo(qu), g1 = k1 + bfhi(qu);         \
        float e0 = __expf(-g0), e1 = __expf(-g1);             \
        a0 += __fdividef(bflo(vu), 1.f + e0);                 \
        a1 += __fdividef(bfhi(vu), 1.f + e1);                 \
    }

    int j = off[d], s1 = off[d + 1];
    for (; j + 4 <= s1; j += 4) {
        int sA = esrc[j], sB = esrc[j + 1], sC = esrc[j + 2], sD = esrc[j + 3];
        unsigned int qA = qw[(size_t)sA * 64 + lane], vA = vw[(size_t)sA * 64 + lane];
        unsigned int qB = qw[(size_t)sB * 64 + lane], vB = vw[(size_t)sB * 64 + lane];
        unsigned int qC = qw[(size_t)sC * 64 + lane], vC = vw[(size_t)sC * 64 + lane];
        unsigned int qD = qw[(size_t)sD * 64 + lane], vD = vw[(size_t)sD * 64 + lane];
        EDGE(qA, vA); EDGE(qB, vB); EDGE(qC, vC); EDGE(qD, vD);
    }
    for (; j < s1; ++j) {
        int s = esrc[j];
        unsigned int qu = qw[(size_t)s * 64 + lane], vu = vw[(size_t)s * 64 + lane];
        EDGE(qu, vu);
    }
#undef EDGE

    float2* sp = (float2*)(S + (size_t)d * HDIM) + lane;
    float2 old = *sp;
    old.x += a0; old.y += a1;
    *sp = old;
}

// ---------------------------------------------------------------------------
// stats: per-channel sum / sumsq of S
// ---------------------------------------------------------------------------
__global__ void stats_kernel(const float* __restrict__ s,
                             float* __restrict__ stats, int n) {
    int c = threadIdx.x & 127, rh = threadIdx.x >> 7;
    int r0 = blockIdx.x * 128;
    int r1 = min(r0 + 128, n);
    float sum = 0.f, sq = 0.f;
    for (int r = r0 + rh; r < r1; r += 2) {
        float v = s[(size_t)r * HDIM + c];
        sum += v;
        sq = fmaf(v, v, sq);
    }
    __shared__ float ls[2][HDIM], lq[2][HDIM];
    ls[rh][c] = sum;
    lq[rh][c] = sq;
    __syncthreads();
    if (rh == 0) {
        atomicAdd(&stats[c], ls[0][c] + ls[1][c]);
        atomicAdd(&stats[HDIM + c], lq[0][c] + lq[1][c]);
    }
}

// ---------------------------------------------------------------------------
// bn_relu: h = relu(gamma * (s - mean) * rsqrt(var + eps) + beta) -> bf16 h
// ---------------------------------------------------------------------------
__global__ void bn_relu_kernel(const float* __restrict__ s,
                               const float* __restrict__ stats,
                               const float* __restrict__ gamma,
                               const float* __restrict__ beta,
                               __hip_bfloat16* __restrict__ out, int n) {
    size_t idx = (size_t)blockIdx.x * 256 + threadIdx.x;
    size_t total = (size_t)n * HDIM;
    if (idx >= total) return;
    int c = (int)(idx & 127);
    float invn = 1.f / (float)n;
    float mean = stats[c] * invn;
    float var = stats[HDIM + c] * invn - mean * mean;
    float sc = gamma[c] * rsqrtf(var + BN_EPS);
    float sh = beta[c] - mean * sc;
    float v = fmaf(s[idx], sc, sh);
    out[idx] = __float2bfloat16(fmaxf(v, 0.f));
}

// ---------------------------------------------------------------------------
// head: out = h @ head_w + head_b   [n,128] @ [128,32], h is bf16
// ---------------------------------------------------------------------------
__global__ void head_kernel(const __hip_bfloat16* __restrict__ h,
                            const float* __restrict__ w,
                            const float* __restrict__ b,
                            float* __restrict__ out, int n) {
    __shared__ float hsm[8][HDIM];
    for (int i = threadIdx.x; i < 8 * HDIM; i += 256) {
        int r = i >> 7, c = i & 127;
        int node = blockIdx.x * 8 + r;
        hsm[r][c] = (node < n) ? __bfloat162float(h[(size_t)node * HDIM + c]) : 0.f;
    }
    __syncthreads();
    int c = threadIdx.x & 31;
    int ng = threadIdx.x >> 5;
    int node = blockIdx.x * 8 + ng;
    if (node >= n) return;
    float acc = b[c];
#pragma unroll
    for (int k = 0; k < HDIM; ++k)
        acc = fmaf(hsm[ng][k], w[k * OCDIM + c], acc);
    out[(size_t)node * OCDIM + c] = acc;
}

// ---------------------------------------------------------------------------
extern "C" void kernel_launch(void* const* d_in, const int* in_sizes, int n_in,
                              void* d_out, int out_size, void* d_ws, size_t ws_size,
                              hipStream_t stream) {
    const float* x      = (const float*)d_in[0];
    const int*   ei     = (const int*)  d_in[1];
    const float* proj_w = (const float*)d_in[2];
    const float* proj_b = (const float*)d_in[3];
    const float* conv_w = (const float*)d_in[4];  // [3][4][128][128]
    const float* conv_b = (const float*)d_in[5];  // [3][4][128]
    const float* bn_g   = (const float*)d_in[6];
    const float* bn_b   = (const float*)d_in[7];
    const float* head_w = (const float*)d_in[8];
    const float* head_b = (const float*)d_in[9];
    float* out = (float*)d_out;

    int n = in_sizes[0] / ICDIM;   // 50000
    int e = in_sizes[1] / 2;       // 600000

    size_t nh = (size_t)n * HDIM;
    size_t need = nh * 4 + 768 * 4 + 4 * nh * 2 + (size_t)12 * HDIM * HDIM * 2
                + ((size_t)3 * n + (n + 1) + 256 + e) * 4;
    if (ws_size < need) return;

    float* S  = (float*)d_ws;
    float* st = S + nh;                         // 3 x (sum[128], sumsq[128])
    __hip_bfloat16* h = (__hip_bfloat16*)(st + 768);
    __hip_bfloat16* K = h + nh;
    __hip_bfloat16* Q = K + nh;
    __hip_bfloat16* V = Q + nh;
    __hip_bfloat16* Wt = V + nh;                // [3][4][128out][128in]

    int* deg    = (int*)(Wt + (size_t)12 * HDIM * HDIM);
    int* incl   = deg + n;
    int* off    = incl + n;                     // n+1
    int* cursor = off + n + 1;
    int* bsum   = cursor + n;                   // 256
    int* esrc   = bsum + 256;                   // e

    hipMemsetAsync(st, 0, 768 * sizeof(float), stream);
    hipMemsetAsync(deg, 0, (size_t)n * sizeof(int), stream);

    int gb_e = (e + 255) / 256;
    int gb_n = (n + 255) / 256;   // 196 <= 256, scan2 ok

    proj_kernel<<<(n + 1) / 2, 256, 0, stream>>>(x, proj_w, proj_b, h, n);
    wconv_kernel<<<12, 256, 0, stream>>>(conv_w, Wt);

    hist_kernel<<<gb_e, 256, 0, stream>>>(ei, deg, e);
    scan1_kernel<<<gb_n, 256, 0, stream>>>(deg, incl, bsum, n);
    scan2_kernel<<<1, 256, 0, stream>>>(bsum, gb_n);
    scan3_kernel<<<gb_n, 256, 0, stream>>>(deg, incl, bsum, off, cursor, n, e);
    scatter_kernel<<<gb_e, 256, 0, stream>>>(ei, cursor, esrc, e);

    int gm = (n + 63) / 64;
    for (int l = 0; l < 3; ++l) {
        gemm4_mfma_kernel<<<dim3(gm, 4), 256, 0, stream>>>(
            h, Wt + (size_t)l * 4 * HDIM * HDIM, conv_b + (size_t)l * 4 * HDIM,
            K, Q, V, S, n);
        agg_kernel<<<(n + 3) / 4, 256, 0, stream>>>(off, esrc, K, Q, V, S, n);
        stats_kernel<<<(n + 127) / 128, 256, 0, stream>>>(S, st + l * 256, n);
        bn_relu_kernel<<<(int)((nh + 255) / 256), 256, 0, stream>>>(
            S, st + l * 256, bn_g + l * HDIM, bn_b + l * HDIM, h, n);
    }

    head_kernel<<<(n + 7) / 8, 256, 0, stream>>>(h, head_w, head_b, out, n);
}

// Round 5
// 537.042 us; speedup vs baseline: 2.4443x; 1.1867x over previous
//
#include <hip/hip_runtime.h>
#include <hip/hip_bf16.h>
#include <math.h>

#define HDIM 128
#define ICDIM 64
#define OCDIM 32
#define BN_EPS 1e-5f
#define NCH 64   // nodes per gemm4 block

typedef __attribute__((ext_vector_type(8))) short bv8;   // 8 x bf16 bits (4 VGPR)
typedef __attribute__((ext_vector_type(4))) float fv4;   // MFMA accumulator

static __device__ __forceinline__ unsigned short f2bf(float v) {
    __hip_bfloat16 t = __float2bfloat16(v);
    return *(unsigned short*)&t;
}
static __device__ __forceinline__ float bflo(unsigned int u) {
    union { unsigned int i; float f; } c; c.i = u << 16; return c.f;
}
static __device__ __forceinline__ float bfhi(unsigned int u) {
    union { unsigned int i; float f; } c; c.i = u & 0xffff0000u; return c.f;
}

// ---------------------------------------------------------------------------
// proj: h = relu(x @ proj_w + proj_b)  -> bf16 h
// ---------------------------------------------------------------------------
__global__ void proj_kernel(const float* __restrict__ x,
                            const float* __restrict__ w,
                            const float* __restrict__ b,
                            __hip_bfloat16* __restrict__ h, int n) {
    __shared__ float xs[2][ICDIM];
    int tid = threadIdx.x;
    if (tid < 2 * ICDIM) {
        int r = tid / ICDIM, c = tid % ICDIM;
        int node = blockIdx.x * 2 + r;
        xs[r][c] = (node < n) ? x[(size_t)node * ICDIM + c] : 0.f;
    }
    __syncthreads();
    int node = blockIdx.x * 2 + (tid >> 7);
    if (node >= n) return;
    int c = tid & 127;
    const float* xr = xs[tid >> 7];
    float acc = b[c];
#pragma unroll
    for (int k = 0; k < ICDIM; ++k)
        acc = fmaf(xr[k], w[k * HDIM + c], acc);
    h[(size_t)node * HDIM + c] = __float2bfloat16(fmaxf(acc, 0.f));
}

// ---------------------------------------------------------------------------
// wconv: conv_w [12][128in][128out] f32  ->  Wt [12][128out][128in] bf16
// ---------------------------------------------------------------------------
__global__ void wconv_kernel(const float* __restrict__ src,
                             __hip_bfloat16* __restrict__ dst) {
    int mat = blockIdx.x;  // 0..11
    const float* s = src + (size_t)mat * HDIM * HDIM;
    __hip_bfloat16* d = dst + (size_t)mat * HDIM * HDIM;
    for (int idx = threadIdx.x; idx < HDIM * HDIM; idx += 256) {
        int i = idx >> 7, o = idx & 127;          // coalesced read
        d[(size_t)o * HDIM + i] = __float2bfloat16(s[idx]);
    }
}

// ---------------------------------------------------------------------------
// gemm4_fused: one block = 64 nodes x all 4 lins.
//   16 waves = 4 lins x 4 out-slices (32 ch). Weights live in registers
//   (loaded once per block); h tile staged in LDS once; 4 node-tiles inner.
//   lin 0,1,2 -> bf16 K,Q,V ; lin 3 -> f32 S (skip, doubles as agg buffer).
// ---------------------------------------------------------------------------
__global__ __launch_bounds__(1024)
void gemm4_fused_kernel(const __hip_bfloat16* __restrict__ hB,
                        const __hip_bfloat16* __restrict__ wt4, // [4][128o][128i]
                        const float* __restrict__ b4,           // [4][128]
                        __hip_bfloat16* __restrict__ K,
                        __hip_bfloat16* __restrict__ Q,
                        __hip_bfloat16* __restrict__ V,
                        float* __restrict__ S, int n) {
    __shared__ unsigned short hs[NCH * HDIM];   // 16 KB, linear
    const unsigned short* h = (const unsigned short*)hB;
    int tid = threadIdx.x;
    int m0 = blockIdx.x * NCH;

    // stage h tile: 16 KB = 1024 threads x 16 B, fully coalesced
    {
        const uint4* src = (const uint4*)(h + (size_t)m0 * HDIM);
        ((uint4*)hs)[tid] = src[tid];
    }

    int wv = tid >> 6;          // 0..15
    int lane = tid & 63;
    int lin = wv >> 2;          // 0..3
    int g2 = wv & 3;            // out-channel slice: channels g2*32 .. +31
    int j = lane & 15;          // node-in-tile (B col, D col)
    int kg = lane >> 4;         // k-group

    // A-operand in registers: rows g2*32 + gs*16 + j, all K (once per block)
    const unsigned short* wbase =
        (const unsigned short*)(wt4 + (size_t)lin * HDIM * HDIM);
    bv8 af[2][4];
#pragma unroll
    for (int gs = 0; gs < 2; ++gs)
#pragma unroll
        for (int ks = 0; ks < 4; ++ks)
            af[gs][ks] = *(const bv8*)(wbase +
                (size_t)(g2 * 32 + gs * 16 + j) * HDIM + ks * 32 + kg * 8);

    const float* bl = b4 + lin * HDIM;
    float4 bias0 = *(const float4*)(bl + g2 * 32 + kg * 4);
    float4 bias1 = *(const float4*)(bl + g2 * 32 + 16 + kg * 4);

    __hip_bfloat16* obf = (lin == 0) ? K : (lin == 1) ? Q : V;

    __syncthreads();

#pragma unroll
    for (int t4 = 0; t4 < NCH / 16; ++t4) {
        const unsigned short* hrow = hs + (t4 * 16 + j) * HDIM + kg * 8;
        fv4 acc0 = (fv4){0.f, 0.f, 0.f, 0.f};
        fv4 acc1 = (fv4){0.f, 0.f, 0.f, 0.f};
#pragma unroll
        for (int ks = 0; ks < 4; ++ks) {
            bv8 bf = *(const bv8*)(hrow + ks * 32);
            acc0 = __builtin_amdgcn_mfma_f32_16x16x32_bf16(af[0][ks], bf, acc0, 0, 0, 0);
            acc1 = __builtin_amdgcn_mfma_f32_16x16x32_bf16(af[1][ks], bf, acc1, 0, 0, 0);
        }
        int node = m0 + t4 * 16 + j;
        if (node < n) {
            if (lin == 3) {
                float* o = S + (size_t)node * HDIM + g2 * 32 + kg * 4;
                float4 r0, r1;
                r0.x = acc0.x + bias0.x; r0.y = acc0.y + bias0.y;
                r0.z = acc0.z + bias0.z; r0.w = acc0.w + bias0.w;
                r1.x = acc1.x + bias1.x; r1.y = acc1.y + bias1.y;
                r1.z = acc1.z + bias1.z; r1.w = acc1.w + bias1.w;
                *(float4*)o = r0;
                *(float4*)(o + 16) = r1;
            } else {
                unsigned short* o =
                    (unsigned short*)obf + (size_t)node * HDIM + g2 * 32 + kg * 4;
                ushort4 r0, r1;
                r0.x = f2bf(acc0.x + bias0.x); r0.y = f2bf(acc0.y + bias0.y);
                r0.z = f2bf(acc0.z + bias0.z); r0.w = f2bf(acc0.w + bias0.w);
                r1.x = f2bf(acc1.x + bias1.x); r1.y = f2bf(acc1.y + bias1.y);
                r1.z = f2bf(acc1.z + bias1.z); r1.w = f2bf(acc1.w + bias1.w);
                *(ushort4*)o = r0;
                *(ushort4*)(o + 16) = r1;
            }
        }
    }
}

// ---------------------------------------------------------------------------
// counting sort of edges by dst: hist -> scan(3 kernels) -> scatter
// ---------------------------------------------------------------------------
__global__ void hist_kernel(const int* __restrict__ ei, int* __restrict__ deg, int e) {
    int i = blockIdx.x * 256 + threadIdx.x;
    if (i < e) atomicAdd(&deg[ei[(size_t)e + i]], 1);
}

__global__ void scan1_kernel(const int* __restrict__ deg, int* __restrict__ incl,
                             int* __restrict__ bsum, int n) {
    __shared__ int tmp[256];
    int i = blockIdx.x * 256 + threadIdx.x;
    int v = (i < n) ? deg[i] : 0;
    tmp[threadIdx.x] = v;
    __syncthreads();
    for (int ofs = 1; ofs < 256; ofs <<= 1) {
        int t = (threadIdx.x >= ofs) ? tmp[threadIdx.x - ofs] : 0;
        __syncthreads();
        tmp[threadIdx.x] += t;
        __syncthreads();
    }
    if (i < n) incl[i] = tmp[threadIdx.x];
    if (threadIdx.x == 255) bsum[blockIdx.x] = tmp[255];
}

__global__ void scan2_kernel(int* __restrict__ bsum, int nb) {
    __shared__ int tmp[256];
    int v = (threadIdx.x < nb) ? bsum[threadIdx.x] : 0;
    tmp[threadIdx.x] = v;
    __syncthreads();
    for (int ofs = 1; ofs < 256; ofs <<= 1) {
        int t = (threadIdx.x >= ofs) ? tmp[threadIdx.x - ofs] : 0;
        __syncthreads();
        tmp[threadIdx.x] += t;
        __syncthreads();
    }
    if (threadIdx.x < nb) bsum[threadIdx.x] = tmp[threadIdx.x] - v;  // exclusive
}

__global__ void scan3_kernel(const int* __restrict__ deg, const int* __restrict__ incl,
                             const int* __restrict__ bsum, int* __restrict__ off,
                             int* __restrict__ cursor, int n, int e) {
    int i = blockIdx.x * 256 + threadIdx.x;
    if (i < n) {
        int ex = incl[i] - deg[i] + bsum[blockIdx.x];
        off[i] = ex;
        cursor[i] = ex;
        if (i == n - 1) off[n] = e;
    }
}

__global__ void scatter_kernel(const int* __restrict__ ei, int* __restrict__ cursor,
                               int* __restrict__ esrc, int e) {
    int i = blockIdx.x * 256 + threadIdx.x;
    if (i < e) {
        int dst = ei[(size_t)e + i];
        int pos = atomicAdd(&cursor[dst], 1);
        esrc[pos] = ei[i];
    }
}

// ---------------------------------------------------------------------------
// agg: S[d] += sum_{j in seg(d)} sigmoid(k[d] + q[src_j]) * v[src_j]
// one wave per dst, 2 channels per lane (bf16x2), unroll x4 with prefetch
// ---------------------------------------------------------------------------
__global__ void agg_kernel(const int* __restrict__ off, const int* __restrict__ esrc,
                           const __hip_bfloat16* __restrict__ kb,
                           const __hip_bfloat16* __restrict__ qb,
                           const __hip_bfloat16* __restrict__ vb,
                           float* __restrict__ S, int n) {
    int d = blockIdx.x * 4 + (threadIdx.x >> 6);
    if (d >= n) return;
    int lane = threadIdx.x & 63;
    const unsigned int* qw = (const unsigned int*)qb;   // [node][64] words
    const unsigned int* vw = (const unsigned int*)vb;
    unsigned int kwu = ((const unsigned int*)kb)[(size_t)d * 64 + lane];
    float k0 = bflo(kwu), k1 = bfhi(kwu);
    float a0 = 0.f, a1 = 0.f;

#define EDGE(qu, vu)                                          \
    {                                                         \
        float g0 = k0 + bflo(qu), g1 = k1 + bfhi(qu);         \
        float e0 = __expf(-g0), e1 = __expf(-g1);             \
        a0 += __fdividef(bflo(vu), 1.f + e0);                 \
        a1 += __fdividef(bfhi(vu), 1.f + e1);                 \
    }

    int j = off[d], s1 = off[d + 1];
    for (; j + 4 <= s1; j += 4) {
        int sA = esrc[j], sB = esrc[j + 1], sC = esrc[j + 2], sD = esrc[j + 3];
        unsigned int qA = qw[(size_t)sA * 64 + lane], vA = vw[(size_t)sA * 64 + lane];
        unsigned int qB = qw[(size_t)sB * 64 + lane], vB = vw[(size_t)sB * 64 + lane];
        unsigned int qC = qw[(size_t)sC * 64 + lane], vC = vw[(size_t)sC * 64 + lane];
        unsigned int qD = qw[(size_t)sD * 64 + lane], vD = vw[(size_t)sD * 64 + lane];
        EDGE(qA, vA); EDGE(qB, vB); EDGE(qC, vC); EDGE(qD, vD);
    }
    for (; j < s1; ++j) {
        int s = esrc[j];
        unsigned int qu = qw[(size_t)s * 64 + lane], vu = vw[(size_t)s * 64 + lane];
        EDGE(qu, vu);
    }
#undef EDGE

    float2* sp = (float2*)(S + (size_t)d * HDIM) + lane;
    float2 old = *sp;
    old.x += a0; old.y += a1;
    *sp = old;
}

// ---------------------------------------------------------------------------
// stats: per-channel sum / sumsq of S
// ---------------------------------------------------------------------------
__global__ void stats_kernel(const float* __restrict__ s,
                             float* __restrict__ stats, int n) {
    int c = threadIdx.x & 127, rh = threadIdx.x >> 7;
    int r0 = blockIdx.x * 128;
    int r1 = min(r0 + 128, n);
    float sum = 0.f, sq = 0.f;
    for (int r = r0 + rh; r < r1; r += 2) {
        float v = s[(size_t)r * HDIM + c];
        sum += v;
        sq = fmaf(v, v, sq);
    }
    __shared__ float ls[2][HDIM], lq[2][HDIM];
    ls[rh][c] = sum;
    lq[rh][c] = sq;
    __syncthreads();
    if (rh == 0) {
        atomicAdd(&stats[c], ls[0][c] + ls[1][c]);
        atomicAdd(&stats[HDIM + c], lq[0][c] + lq[1][c]);
    }
}

// ---------------------------------------------------------------------------
// bn_relu: h = relu(gamma * (s - mean) * rsqrt(var + eps) + beta) -> bf16 h
// ---------------------------------------------------------------------------
__global__ void bn_relu_kernel(const float* __restrict__ s,
                               const float* __restrict__ stats,
                               const float* __restrict__ gamma,
                               const float* __restrict__ beta,
                               __hip_bfloat16* __restrict__ out, int n) {
    size_t idx = (size_t)blockIdx.x * 256 + threadIdx.x;
    size_t total = (size_t)n * HDIM;
    if (idx >= total) return;
    int c = (int)(idx & 127);
    float invn = 1.f / (float)n;
    float mean = stats[c] * invn;
    float var = stats[HDIM + c] * invn - mean * mean;
    float sc = gamma[c] * rsqrtf(var + BN_EPS);
    float sh = beta[c] - mean * sc;
    float v = fmaf(s[idx], sc, sh);
    out[idx] = __float2bfloat16(fmaxf(v, 0.f));
}

// ---------------------------------------------------------------------------
// head: out = h @ head_w + head_b   [n,128] @ [128,32], h is bf16
// ---------------------------------------------------------------------------
__global__ void head_kernel(const __hip_bfloat16* __restrict__ h,
                            const float* __restrict__ w,
                            const float* __restrict__ b,
                            float* __restrict__ out, int n) {
    __shared__ float hsm[8][HDIM];
    for (int i = threadIdx.x; i < 8 * HDIM; i += 256) {
        int r = i >> 7, c = i & 127;
        int node = blockIdx.x * 8 + r;
        hsm[r][c] = (node < n) ? __bfloat162float(h[(size_t)node * HDIM + c]) : 0.f;
    }
    __syncthreads();
    int c = threadIdx.x & 31;
    int ng = threadIdx.x >> 5;
    int node = blockIdx.x * 8 + ng;
    if (node >= n) return;
    float acc = b[c];
#pragma unroll
    for (int k = 0; k < HDIM; ++k)
        acc = fmaf(hsm[ng][k], w[k * OCDIM + c], acc);
    out[(size_t)node * OCDIM + c] = acc;
}

// ---------------------------------------------------------------------------
extern "C" void kernel_launch(void* const* d_in, const int* in_sizes, int n_in,
                              void* d_out, int out_size, void* d_ws, size_t ws_size,
                              hipStream_t stream) {
    const float* x      = (const float*)d_in[0];
    const int*   ei     = (const int*)  d_in[1];
    const float* proj_w = (const float*)d_in[2];
    const float* proj_b = (const float*)d_in[3];
    const float* conv_w = (const float*)d_in[4];  // [3][4][128][128]
    const float* conv_b = (const float*)d_in[5];  // [3][4][128]
    const float* bn_g   = (const float*)d_in[6];
    const float* bn_b   = (const float*)d_in[7];
    const float* head_w = (const float*)d_in[8];
    const float* head_b = (const float*)d_in[9];
    float* out = (float*)d_out;

    int n = in_sizes[0] / ICDIM;   // 50000
    int e = in_sizes[1] / 2;       // 600000

    size_t nh = (size_t)n * HDIM;
    size_t need = nh * 4 + 768 * 4 + 4 * nh * 2 + (size_t)12 * HDIM * HDIM * 2
                + ((size_t)3 * n + (n + 1) + 256 + e) * 4;
    if (ws_size < need) return;

    float* S  = (float*)d_ws;
    float* st = S + nh;                         // 3 x (sum[128], sumsq[128])
    __hip_bfloat16* h = (__hip_bfloat16*)(st + 768);
    __hip_bfloat16* K = h + nh;
    __hip_bfloat16* Q = K + nh;
    __hip_bfloat16* V = Q + nh;
    __hip_bfloat16* Wt = V + nh;                // [3][4][128out][128in]

    int* deg    = (int*)(Wt + (size_t)12 * HDIM * HDIM);
    int* incl   = deg + n;
    int* off    = incl + n;                     // n+1
    int* cursor = off + n + 1;
    int* bsum   = cursor + n;                   // 256
    int* esrc   = bsum + 256;                   // e

    hipMemsetAsync(st, 0, 768 * sizeof(float), stream);
    hipMemsetAsync(deg, 0, (size_t)n * sizeof(int), stream);

    int gb_e = (e + 255) / 256;
    int gb_n = (n + 255) / 256;   // 196 <= 256, scan2 ok

    proj_kernel<<<(n + 1) / 2, 256, 0, stream>>>(x, proj_w, proj_b, h, n);
    wconv_kernel<<<12, 256, 0, stream>>>(conv_w, Wt);

    hist_kernel<<<gb_e, 256, 0, stream>>>(ei, deg, e);
    scan1_kernel<<<gb_n, 256, 0, stream>>>(deg, incl, bsum, n);
    scan2_kernel<<<1, 256, 0, stream>>>(bsum, gb_n);
    scan3_kernel<<<gb_n, 256, 0, stream>>>(deg, incl, bsum, off, cursor, n, e);
    scatter_kernel<<<gb_e, 256, 0, stream>>>(ei, cursor, esrc, e);

    int gm = (n + NCH - 1) / NCH;
    for (int l = 0; l < 3; ++l) {
        gemm4_fused_kernel<<<gm, 1024, 0, stream>>>(
            h, Wt + (size_t)l * 4 * HDIM * HDIM, conv_b + (size_t)l * 4 * HDIM,
            K, Q, V, S, n);
        agg_kernel<<<(n + 3) / 4, 256, 0, stream>>>(off, esrc, K, Q, V, S, n);
        stats_kernel<<<(n + 127) / 128, 256, 0, stream>>>(S, st + l * 256, n);
        bn_relu_kernel<<<(int)((nh + 255) / 256), 256, 0, stream>>>(
            S, st + l * 256, bn_g + l * HDIM, bn_b + l * HDIM, h, n);
    }

    head_kernel<<<(n + 7) / 8, 256, 0, stream>>>(h, head_w, head_b, out, n);
}

// Round 6
// 531.791 us; speedup vs baseline: 2.4684x; 1.0099x over previous
//
#include <hip/hip_runtime.h>
#include <hip/hip_bf16.h>
#include <math.h>

#define HDIM 128
#define ICDIM 64
#define OCDIM 32
#define BN_EPS 1e-5f
#define NCH 64   // nodes per gemm block

typedef __attribute__((ext_vector_type(8))) short bv8;   // 8 x bf16 bits (4 VGPR)
typedef __attribute__((ext_vector_type(4))) float fv4;   // MFMA accumulator

static __device__ __forceinline__ unsigned short f2bf(float v) {
    __hip_bfloat16 t = __float2bfloat16(v);
    return *(unsigned short*)&t;
}
static __device__ __forceinline__ float bflo(unsigned int u) {
    union { unsigned int i; float f; } c; c.i = u << 16; return c.f;
}
static __device__ __forceinline__ float bfhi(unsigned int u) {
    union { unsigned int i; float f; } c; c.i = u & 0xffff0000u; return c.f;
}
static __device__ __forceinline__ unsigned int pack2bf(float a, float b) {
    return (unsigned int)f2bf(a) | ((unsigned int)f2bf(b) << 16);
}

// ---------------------------------------------------------------------------
// wconv: conv_w [12][128in][128out] f32 -> Wt [12][128out][128in] bf16
// ---------------------------------------------------------------------------
__global__ void wconv_kernel(const float* __restrict__ src,
                             __hip_bfloat16* __restrict__ dst) {
    int mat = blockIdx.x;  // 0..11
    const float* s = src + (size_t)mat * HDIM * HDIM;
    __hip_bfloat16* d = dst + (size_t)mat * HDIM * HDIM;
    for (int idx = threadIdx.x; idx < HDIM * HDIM; idx += 256) {
        int i = idx >> 7, o = idx & 127;          // coalesced read
        d[(size_t)o * HDIM + i] = __float2bfloat16(s[idx]);
    }
}

// wpconv: proj_w [64in][128out] f32 -> Wp [128out][64in] bf16
__global__ void wpconv_kernel(const float* __restrict__ src,
                              __hip_bfloat16* __restrict__ dst) {
    for (int idx = threadIdx.x; idx < ICDIM * HDIM; idx += 256) {
        int i = idx >> 7, o = idx & 127;
        dst[(size_t)o * ICDIM + i] = __float2bfloat16(src[idx]);
    }
}

// ---------------------------------------------------------------------------
// proj_mfma: h = relu(x @ proj_w + proj_b) -> bf16 h
//   block = 256 thr = 4 waves; 64 nodes/block; x tile staged to LDS as bf16;
//   wave w owns out-channels w*32..+31 with weights in registers.
// ---------------------------------------------------------------------------
__global__ __launch_bounds__(256)
void proj_mfma_kernel(const float* __restrict__ x,
                      const __hip_bfloat16* __restrict__ wp,  // [128o][64i]
                      const float* __restrict__ b,
                      __hip_bfloat16* __restrict__ h, int n) {
    __shared__ unsigned int xs[NCH * ICDIM / 2];   // 8 KB bf16, linear [node][64]
    int tid = threadIdx.x;
    int m0 = blockIdx.x * NCH;

    // stage + convert: 64 nodes x 64 ch f32 -> bf16; float2 per uint
    const float2* xsrc = (const float2*)(x + (size_t)m0 * ICDIM);
    for (int i = tid; i < NCH * ICDIM / 2; i += 256) {
        int node = m0 + (i >> 5);
        float2 v = (node < n) ? xsrc[i] : (float2){0.f, 0.f};
        xs[i] = pack2bf(v.x, v.y);
    }

    int wv = tid >> 6;          // 0..3  -> out-ch slice wv*32
    int lane = tid & 63;
    int j = lane & 15;          // node-in-tile
    int kg = lane >> 4;         // k-group

    bv8 af[2][2];
#pragma unroll
    for (int gs = 0; gs < 2; ++gs)
#pragma unroll
        for (int ks = 0; ks < 2; ++ks)
            af[gs][ks] = *(const bv8*)((const unsigned short*)wp +
                (size_t)(wv * 32 + gs * 16 + j) * ICDIM + ks * 32 + kg * 8);

    float4 bias0 = *(const float4*)(b + wv * 32 + kg * 4);
    float4 bias1 = *(const float4*)(b + wv * 32 + 16 + kg * 4);

    __syncthreads();

#pragma unroll
    for (int t4 = 0; t4 < NCH / 16; ++t4) {
        const unsigned short* xrow =
            (const unsigned short*)xs + (t4 * 16 + j) * ICDIM + kg * 8;
        fv4 acc0 = (fv4){0.f, 0.f, 0.f, 0.f};
        fv4 acc1 = (fv4){0.f, 0.f, 0.f, 0.f};
#pragma unroll
        for (int ks = 0; ks < 2; ++ks) {
            bv8 bf = *(const bv8*)(xrow + ks * 32);
            acc0 = __builtin_amdgcn_mfma_f32_16x16x32_bf16(af[0][ks], bf, acc0, 0, 0, 0);
            acc1 = __builtin_amdgcn_mfma_f32_16x16x32_bf16(af[1][ks], bf, acc1, 0, 0, 0);
        }
        int node = m0 + t4 * 16 + j;
        if (node < n) {
            unsigned short* o =
                (unsigned short*)h + (size_t)node * HDIM + wv * 32 + kg * 4;
            ushort4 r0, r1;
            r0.x = f2bf(fmaxf(acc0.x + bias0.x, 0.f));
            r0.y = f2bf(fmaxf(acc0.y + bias0.y, 0.f));
            r0.z = f2bf(fmaxf(acc0.z + bias0.z, 0.f));
            r0.w = f2bf(fmaxf(acc0.w + bias0.w, 0.f));
            r1.x = f2bf(fmaxf(acc1.x + bias1.x, 0.f));
            r1.y = f2bf(fmaxf(acc1.y + bias1.y, 0.f));
            r1.z = f2bf(fmaxf(acc1.z + bias1.z, 0.f));
            r1.w = f2bf(fmaxf(acc1.w + bias1.w, 0.f));
            *(ushort4*)o = r0;
            *(ushort4*)(o + 16) = r1;
        }
    }
}

// ---------------------------------------------------------------------------
// gemm4_fused: one block = 64 nodes x all 4 lins.
//   16 waves = 4 lins x 4 out-slices (32 ch). Weights in registers;
//   h tile staged in LDS once; 4 node-tiles inner.
//   lin 0,1,2 -> bf16 K,Q,V ; lin 3 -> f32 S (skip, doubles as agg buffer).
// ---------------------------------------------------------------------------
__global__ __launch_bounds__(1024)
void gemm4_fused_kernel(const __hip_bfloat16* __restrict__ hB,
                        const __hip_bfloat16* __restrict__ wt4, // [4][128o][128i]
                        const float* __restrict__ b4,           // [4][128]
                        __hip_bfloat16* __restrict__ K,
                        __hip_bfloat16* __restrict__ Q,
                        __hip_bfloat16* __restrict__ V,
                        float* __restrict__ S, int n) {
    __shared__ unsigned short hs[NCH * HDIM];   // 16 KB, linear
    const unsigned short* h = (const unsigned short*)hB;
    int tid = threadIdx.x;
    int m0 = blockIdx.x * NCH;

    // stage h tile: 16 KB = 1024 threads x 16 B, fully coalesced
    {
        const uint4* src = (const uint4*)(h + (size_t)m0 * HDIM);
        ((uint4*)hs)[tid] = src[tid];
    }

    int wv = tid >> 6;          // 0..15
    int lane = tid & 63;
    int lin = wv >> 2;          // 0..3
    int g2 = wv & 3;            // out-channel slice: channels g2*32 .. +31
    int j = lane & 15;          // node-in-tile (B col, D col)
    int kg = lane >> 4;         // k-group

    const unsigned short* wbase =
        (const unsigned short*)(wt4 + (size_t)lin * HDIM * HDIM);
    bv8 af[2][4];
#pragma unroll
    for (int gs = 0; gs < 2; ++gs)
#pragma unroll
        for (int ks = 0; ks < 4; ++ks)
            af[gs][ks] = *(const bv8*)(wbase +
                (size_t)(g2 * 32 + gs * 16 + j) * HDIM + ks * 32 + kg * 8);

    const float* bl = b4 + lin * HDIM;
    float4 bias0 = *(const float4*)(bl + g2 * 32 + kg * 4);
    float4 bias1 = *(const float4*)(bl + g2 * 32 + 16 + kg * 4);

    __hip_bfloat16* obf = (lin == 0) ? K : (lin == 1) ? Q : V;

    __syncthreads();

#pragma unroll
    for (int t4 = 0; t4 < NCH / 16; ++t4) {
        const unsigned short* hrow = hs + (t4 * 16 + j) * HDIM + kg * 8;
        fv4 acc0 = (fv4){0.f, 0.f, 0.f, 0.f};
        fv4 acc1 = (fv4){0.f, 0.f, 0.f, 0.f};
#pragma unroll
        for (int ks = 0; ks < 4; ++ks) {
            bv8 bf = *(const bv8*)(hrow + ks * 32);
            acc0 = __builtin_amdgcn_mfma_f32_16x16x32_bf16(af[0][ks], bf, acc0, 0, 0, 0);
            acc1 = __builtin_amdgcn_mfma_f32_16x16x32_bf16(af[1][ks], bf, acc1, 0, 0, 0);
        }
        int node = m0 + t4 * 16 + j;
        if (node < n) {
            if (lin == 3) {
                float* o = S + (size_t)node * HDIM + g2 * 32 + kg * 4;
                float4 r0, r1;
                r0.x = acc0.x + bias0.x; r0.y = acc0.y + bias0.y;
                r0.z = acc0.z + bias0.z; r0.w = acc0.w + bias0.w;
                r1.x = acc1.x + bias1.x; r1.y = acc1.y + bias1.y;
                r1.z = acc1.z + bias1.z; r1.w = acc1.w + bias1.w;
                *(float4*)o = r0;
                *(float4*)(o + 16) = r1;
            } else {
                unsigned short* o =
                    (unsigned short*)obf + (size_t)node * HDIM + g2 * 32 + kg * 4;
                ushort4 r0, r1;
                r0.x = f2bf(acc0.x + bias0.x); r0.y = f2bf(acc0.y + bias0.y);
                r0.z = f2bf(acc0.z + bias0.z); r0.w = f2bf(acc0.w + bias0.w);
                r1.x = f2bf(acc1.x + bias1.x); r1.y = f2bf(acc1.y + bias1.y);
                r1.z = f2bf(acc1.z + bias1.z); r1.w = f2bf(acc1.w + bias1.w);
                *(ushort4*)o = r0;
                *(ushort4*)(o + 16) = r1;
            }
        }
    }
}

// ---------------------------------------------------------------------------
// counting sort of edges by dst: hist -> scan(3 kernels) -> scatter
// ---------------------------------------------------------------------------
__global__ void hist_kernel(const int* __restrict__ ei, int* __restrict__ deg, int e) {
    int i = blockIdx.x * 256 + threadIdx.x;
    if (i < e) atomicAdd(&deg[ei[(size_t)e + i]], 1);
}

__global__ void scan1_kernel(const int* __restrict__ deg, int* __restrict__ incl,
                             int* __restrict__ bsum, int n) {
    __shared__ int tmp[256];
    int i = blockIdx.x * 256 + threadIdx.x;
    int v = (i < n) ? deg[i] : 0;
    tmp[threadIdx.x] = v;
    __syncthreads();
    for (int ofs = 1; ofs < 256; ofs <<= 1) {
        int t = (threadIdx.x >= ofs) ? tmp[threadIdx.x - ofs] : 0;
        __syncthreads();
        tmp[threadIdx.x] += t;
        __syncthreads();
    }
    if (i < n) incl[i] = tmp[threadIdx.x];
    if (threadIdx.x == 255) bsum[blockIdx.x] = tmp[255];
}

__global__ void scan2_kernel(int* __restrict__ bsum, int nb) {
    __shared__ int tmp[256];
    int v = (threadIdx.x < nb) ? bsum[threadIdx.x] : 0;
    tmp[threadIdx.x] = v;
    __syncthreads();
    for (int ofs = 1; ofs < 256; ofs <<= 1) {
        int t = (threadIdx.x >= ofs) ? tmp[threadIdx.x - ofs] : 0;
        __syncthreads();
        tmp[threadIdx.x] += t;
        __syncthreads();
    }
    if (threadIdx.x < nb) bsum[threadIdx.x] = tmp[threadIdx.x] - v;  // exclusive
}

__global__ void scan3_kernel(const int* __restrict__ deg, const int* __restrict__ incl,
                             const int* __restrict__ bsum, int* __restrict__ off,
                             int* __restrict__ cursor, int n, int e) {
    int i = blockIdx.x * 256 + threadIdx.x;
    if (i < n) {
        int ex = incl[i] - deg[i] + bsum[blockIdx.x];
        off[i] = ex;
        cursor[i] = ex;
        if (i == n - 1) off[n] = e;
    }
}

__global__ void scatter_kernel(const int* __restrict__ ei, int* __restrict__ cursor,
                               int* __restrict__ esrc, int e) {
    int i = blockIdx.x * 256 + threadIdx.x;
    if (i < e) {
        int dst = ei[(size_t)e + i];
        int pos = atomicAdd(&cursor[dst], 1);
        esrc[pos] = ei[i];
    }
}

// ---------------------------------------------------------------------------
// agg: S[d] += sum_{j in seg(d)} sigmoid(k[d] + q[src_j]) * v[src_j]
// one wave per dst, 2 channels per lane (bf16x2), unroll x8 with prefetch
// ---------------------------------------------------------------------------
__global__ void agg_kernel(const int* __restrict__ off, const int* __restrict__ esrc,
                           const __hip_bfloat16* __restrict__ kb,
                           const __hip_bfloat16* __restrict__ qb,
                           const __hip_bfloat16* __restrict__ vb,
                           float* __restrict__ S, int n) {
    int d = blockIdx.x * 4 + (threadIdx.x >> 6);
    if (d >= n) return;
    int lane = threadIdx.x & 63;
    const unsigned int* qw = (const unsigned int*)qb;   // [node][64] words
    const unsigned int* vw = (const unsigned int*)vb;
    unsigned int kwu = ((const unsigned int*)kb)[(size_t)d * 64 + lane];
    float k0 = bflo(kwu), k1 = bfhi(kwu);
    float a0 = 0.f, a1 = 0.f;

#define EDGE(qu, vu)                                          \
    {                                                         \
        float g0 = k0 + bflo(qu), g1 = k1 + bfhi(qu);         \
        float e0 = __expf(-g0), e1 = __expf(-g1);             \
        a0 += __fdividef(bflo(vu), 1.f + e0);                 \
        a1 += __fdividef(bfhi(vu), 1.f + e1);                 \
    }

    int j = off[d], s1 = off[d + 1];
    for (; j + 8 <= s1; j += 8) {
        int sA = esrc[j],     sB = esrc[j + 1], sC = esrc[j + 2], sD = esrc[j + 3];
        int sE = esrc[j + 4], sF = esrc[j + 5], sG = esrc[j + 6], sH = esrc[j + 7];
        unsigned int qA = qw[(size_t)sA * 64 + lane], vA = vw[(size_t)sA * 64 + lane];
        unsigned int qB = qw[(size_t)sB * 64 + lane], vB = vw[(size_t)sB * 64 + lane];
        unsigned int qC = qw[(size_t)sC * 64 + lane], vC = vw[(size_t)sC * 64 + lane];
        unsigned int qD = qw[(size_t)sD * 64 + lane], vD = vw[(size_t)sD * 64 + lane];
        unsigned int qE = qw[(size_t)sE * 64 + lane], vE = vw[(size_t)sE * 64 + lane];
        unsigned int qF = qw[(size_t)sF * 64 + lane], vF = vw[(size_t)sF * 64 + lane];
        unsigned int qG = qw[(size_t)sG * 64 + lane], vG = vw[(size_t)sG * 64 + lane];
        unsigned int qH = qw[(size_t)sH * 64 + lane], vH = vw[(size_t)sH * 64 + lane];
        EDGE(qA, vA); EDGE(qB, vB); EDGE(qC, vC); EDGE(qD, vD);
        EDGE(qE, vE); EDGE(qF, vF); EDGE(qG, vG); EDGE(qH, vH);
    }
    for (; j + 2 <= s1; j += 2) {
        int sA = esrc[j], sB = esrc[j + 1];
        unsigned int qA = qw[(size_t)sA * 64 + lane], vA = vw[(size_t)sA * 64 + lane];
        unsigned int qB = qw[(size_t)sB * 64 + lane], vB = vw[(size_t)sB * 64 + lane];
        EDGE(qA, vA); EDGE(qB, vB);
    }
    for (; j < s1; ++j) {
        int s = esrc[j];
        unsigned int qu = qw[(size_t)s * 64 + lane], vu = vw[(size_t)s * 64 + lane];
        EDGE(qu, vu);
    }
#undef EDGE

    float2* sp = (float2*)(S + (size_t)d * HDIM) + lane;
    float2 old = *sp;
    old.x += a0; old.y += a1;
    *sp = old;
}

// ---------------------------------------------------------------------------
// stats: per-channel sum / sumsq of S
// ---------------------------------------------------------------------------
__global__ void stats_kernel(const float* __restrict__ s,
                             float* __restrict__ stats, int n) {
    int c = threadIdx.x & 127, rh = threadIdx.x >> 7;
    int r0 = blockIdx.x * 128;
    int r1 = min(r0 + 128, n);
    float sum = 0.f, sq = 0.f;
    for (int r = r0 + rh; r < r1; r += 2) {
        float v = s[(size_t)r * HDIM + c];
        sum += v;
        sq = fmaf(v, v, sq);
    }
    __shared__ float ls[2][HDIM], lq[2][HDIM];
    ls[rh][c] = sum;
    lq[rh][c] = sq;
    __syncthreads();
    if (rh == 0) {
        atomicAdd(&stats[c], ls[0][c] + ls[1][c]);
        atomicAdd(&stats[HDIM + c], lq[0][c] + lq[1][c]);
    }
}

// ---------------------------------------------------------------------------
// bn_relu: h = relu(gamma * (s - mean) * rsqrt(var + eps) + beta) -> bf16 h
// ---------------------------------------------------------------------------
__global__ void bn_relu_kernel(const float* __restrict__ s,
                               const float* __restrict__ stats,
                               const float* __restrict__ gamma,
                               const float* __restrict__ beta,
                               __hip_bfloat16* __restrict__ out, int n) {
    size_t idx = (size_t)blockIdx.x * 256 + threadIdx.x;
    size_t total = (size_t)n * HDIM;
    if (idx >= total) return;
    int c = (int)(idx & 127);
    float invn = 1.f / (float)n;
    float mean = stats[c] * invn;
    float var = stats[HDIM + c] * invn - mean * mean;
    float sc = gamma[c] * rsqrtf(var + BN_EPS);
    float sh = beta[c] - mean * sc;
    float v = fmaf(s[idx], sc, sh);
    out[idx] = __float2bfloat16(fmaxf(v, 0.f));
}

// ---------------------------------------------------------------------------
// head: out = h @ head_w + head_b   [n,128] @ [128,32], h is bf16
// ---------------------------------------------------------------------------
__global__ void head_kernel(const __hip_bfloat16* __restrict__ h,
                            const float* __restrict__ w,
                            const float* __restrict__ b,
                            float* __restrict__ out, int n) {
    __shared__ float hsm[8][HDIM];
    for (int i = threadIdx.x; i < 8 * HDIM; i += 256) {
        int r = i >> 7, c = i & 127;
        int node = blockIdx.x * 8 + r;
        hsm[r][c] = (node < n) ? __bfloat162float(h[(size_t)node * HDIM + c]) : 0.f;
    }
    __syncthreads();
    int c = threadIdx.x & 31;
    int ng = threadIdx.x >> 5;
    int node = blockIdx.x * 8 + ng;
    if (node >= n) return;
    float acc = b[c];
#pragma unroll
    for (int k = 0; k < HDIM; ++k)
        acc = fmaf(hsm[ng][k], w[k * OCDIM + c], acc);
    out[(size_t)node * OCDIM + c] = acc;
}

// ---------------------------------------------------------------------------
extern "C" void kernel_launch(void* const* d_in, const int* in_sizes, int n_in,
                              void* d_out, int out_size, void* d_ws, size_t ws_size,
                              hipStream_t stream) {
    const float* x      = (const float*)d_in[0];
    const int*   ei     = (const int*)  d_in[1];
    const float* proj_w = (const float*)d_in[2];
    const float* proj_b = (const float*)d_in[3];
    const float* conv_w = (const float*)d_in[4];  // [3][4][128][128]
    const float* conv_b = (const float*)d_in[5];  // [3][4][128]
    const float* bn_g   = (const float*)d_in[6];
    const float* bn_b   = (const float*)d_in[7];
    const float* head_w = (const float*)d_in[8];
    const float* head_b = (const float*)d_in[9];
    float* out = (float*)d_out;

    int n = in_sizes[0] / ICDIM;   // 50000
    int e = in_sizes[1] / 2;       // 600000

    size_t nh = (size_t)n * HDIM;
    size_t need = nh * 4 + 768 * 4 + 4 * nh * 2
                + (size_t)12 * HDIM * HDIM * 2 + (size_t)HDIM * ICDIM * 2
                + ((size_t)3 * n + (n + 1) + 256 + e) * 4;
    if (ws_size < need) return;

    float* S  = (float*)d_ws;
    float* st = S + nh;                         // 3 x (sum[128], sumsq[128])
    __hip_bfloat16* h = (__hip_bfloat16*)(st + 768);
    __hip_bfloat16* K = h + nh;
    __hip_bfloat16* Q = K + nh;
    __hip_bfloat16* V = Q + nh;
    __hip_bfloat16* Wt = V + nh;                // [3][4][128out][128in]
    __hip_bfloat16* Wp = Wt + (size_t)12 * HDIM * HDIM;  // [128out][64in]

    int* deg    = (int*)(Wp + (size_t)HDIM * ICDIM);
    int* incl   = deg + n;
    int* off    = incl + n;                     // n+1
    int* cursor = off + n + 1;
    int* bsum   = cursor + n;                   // 256
    int* esrc   = bsum + 256;                   // e

    hipMemsetAsync(st, 0, 768 * sizeof(float), stream);
    hipMemsetAsync(deg, 0, (size_t)n * sizeof(int), stream);

    int gb_e = (e + 255) / 256;
    int gb_n = (n + 255) / 256;   // 196 <= 256, scan2 ok

    wconv_kernel<<<12, 256, 0, stream>>>(conv_w, Wt);
    wpconv_kernel<<<1, 256, 0, stream>>>(proj_w, Wp);
    proj_mfma_kernel<<<(n + NCH - 1) / NCH, 256, 0, stream>>>(x, Wp, proj_b, h, n);

    hist_kernel<<<gb_e, 256, 0, stream>>>(ei, deg, e);
    scan1_kernel<<<gb_n, 256, 0, stream>>>(deg, incl, bsum, n);
    scan2_kernel<<<1, 256, 0, stream>>>(bsum, gb_n);
    scan3_kernel<<<gb_n, 256, 0, stream>>>(deg, incl, bsum, off, cursor, n, e);
    scatter_kernel<<<gb_e, 256, 0, stream>>>(ei, cursor, esrc, e);

    int gm = (n + NCH - 1) / NCH;
    for (int l = 0; l < 3; ++l) {
        gemm4_fused_kernel<<<gm, 1024, 0, stream>>>(
            h, Wt + (size_t)l * 4 * HDIM * HDIM, conv_b + (size_t)l * 4 * HDIM,
            K, Q, V, S, n);
        agg_kernel<<<(n + 3) / 4, 256, 0, stream>>>(off, esrc, K, Q, V, S, n);
        stats_kernel<<<(n + 127) / 128, 256, 0, stream>>>(S, st + l * 256, n);
        bn_relu_kernel<<<(int)((nh + 255) / 256), 256, 0, stream>>>(
            S, st + l * 256, bn_g + l * HDIM, bn_b + l * HDIM, h, n);
    }

    head_kernel<<<(n + 7) / 8, 256, 0, stream>>>(h, head_w, head_b, out, n);
}

// Round 9
// 496.908 us; speedup vs baseline: 2.6417x; 1.0702x over previous
//
#include <hip/hip_runtime.h>
#include <hip/hip_bf16.h>
#include <math.h>

#define HDIM 128
#define ICDIM 64
#define OCDIM 32
#define BN_EPS 1e-5f
#define NCH 64   // nodes per gemm block

typedef __attribute__((ext_vector_type(8))) short bv8;   // 8 x bf16 bits (4 VGPR)
typedef __attribute__((ext_vector_type(4))) float fv4;   // MFMA accumulator

static __device__ __forceinline__ unsigned short f2bf(float v) {
    __hip_bfloat16 t = __float2bfloat16(v);
    return *(unsigned short*)&t;
}
static __device__ __forceinline__ float bflo(unsigned int u) {
    union { unsigned int i; float f; } c; c.i = u << 16; return c.f;
}
static __device__ __forceinline__ float bfhi(unsigned int u) {
    union { unsigned int i; float f; } c; c.i = u & 0xffff0000u; return c.f;
}
static __device__ __forceinline__ unsigned int pack2bf(float a, float b) {
    return (unsigned int)f2bf(a) | ((unsigned int)f2bf(b) << 16);
}

// ---------------------------------------------------------------------------
// wconv: conv_w [12][128in][128out] f32 -> Wt [12][128out][128in] bf16
// ---------------------------------------------------------------------------
__global__ void wconv_kernel(const float* __restrict__ src,
                             __hip_bfloat16* __restrict__ dst) {
    int mat = blockIdx.x;  // 0..11
    const float* s = src + (size_t)mat * HDIM * HDIM;
    __hip_bfloat16* d = dst + (size_t)mat * HDIM * HDIM;
    for (int idx = threadIdx.x; idx < HDIM * HDIM; idx += 256) {
        int i = idx >> 7, o = idx & 127;          // coalesced read
        d[(size_t)o * HDIM + i] = __float2bfloat16(s[idx]);
    }
}

// wpconv: proj_w [64in][128out] f32 -> Wp [128out][64in] bf16
__global__ void wpconv_kernel(const float* __restrict__ src,
                              __hip_bfloat16* __restrict__ dst) {
    for (int idx = threadIdx.x; idx < ICDIM * HDIM; idx += 256) {
        int i = idx >> 7, o = idx & 127;
        dst[(size_t)o * ICDIM + i] = __float2bfloat16(src[idx]);
    }
}

// ---------------------------------------------------------------------------
// proj_mfma: h = relu(x @ proj_w + proj_b) -> bf16 h
// ---------------------------------------------------------------------------
__global__ __launch_bounds__(256)
void proj_mfma_kernel(const float* __restrict__ x,
                      const __hip_bfloat16* __restrict__ wp,  // [128o][64i]
                      const float* __restrict__ b,
                      __hip_bfloat16* __restrict__ h, int n) {
    __shared__ unsigned int xs[NCH * ICDIM / 2];   // 8 KB bf16, linear [node][64]
    int tid = threadIdx.x;
    int m0 = blockIdx.x * NCH;

    const float2* xsrc = (const float2*)(x + (size_t)m0 * ICDIM);
    for (int i = tid; i < NCH * ICDIM / 2; i += 256) {
        int node = m0 + (i >> 5);
        float2 v = (node < n) ? xsrc[i] : (float2){0.f, 0.f};
        xs[i] = pack2bf(v.x, v.y);
    }

    int wv = tid >> 6;          // 0..3  -> out-ch slice wv*32
    int lane = tid & 63;
    int j = lane & 15;          // node-in-tile
    int kg = lane >> 4;         // k-group

    bv8 af[2][2];
#pragma unroll
    for (int gs = 0; gs < 2; ++gs)
#pragma unroll
        for (int ks = 0; ks < 2; ++ks)
            af[gs][ks] = *(const bv8*)((const unsigned short*)wp +
                (size_t)(wv * 32 + gs * 16 + j) * ICDIM + ks * 32 + kg * 8);

    float4 bias0 = *(const float4*)(b + wv * 32 + kg * 4);
    float4 bias1 = *(const float4*)(b + wv * 32 + 16 + kg * 4);

    __syncthreads();

#pragma unroll
    for (int t4 = 0; t4 < NCH / 16; ++t4) {
        const unsigned short* xrow =
            (const unsigned short*)xs + (t4 * 16 + j) * ICDIM + kg * 8;
        fv4 acc0 = (fv4){0.f, 0.f, 0.f, 0.f};
        fv4 acc1 = (fv4){0.f, 0.f, 0.f, 0.f};
#pragma unroll
        for (int ks = 0; ks < 2; ++ks) {
            bv8 bf = *(const bv8*)(xrow + ks * 32);
            acc0 = __builtin_amdgcn_mfma_f32_16x16x32_bf16(af[0][ks], bf, acc0, 0, 0, 0);
            acc1 = __builtin_amdgcn_mfma_f32_16x16x32_bf16(af[1][ks], bf, acc1, 0, 0, 0);
        }
        int node = m0 + t4 * 16 + j;
        if (node < n) {
            unsigned short* o =
                (unsigned short*)h + (size_t)node * HDIM + wv * 32 + kg * 4;
            ushort4 r0, r1;
            r0.x = f2bf(fmaxf(acc0.x + bias0.x, 0.f));
            r0.y = f2bf(fmaxf(acc0.y + bias0.y, 0.f));
            r0.z = f2bf(fmaxf(acc0.z + bias0.z, 0.f));
            r0.w = f2bf(fmaxf(acc0.w + bias0.w, 0.f));
            r1.x = f2bf(fmaxf(acc1.x + bias1.x, 0.f));
            r1.y = f2bf(fmaxf(acc1.y + bias1.y, 0.f));
            r1.z = f2bf(fmaxf(acc1.z + bias1.z, 0.f));
            r1.w = f2bf(fmaxf(acc1.w + bias1.w, 0.f));
            *(ushort4*)o = r0;
            *(ushort4*)(o + 16) = r1;
        }
    }
}

// ---------------------------------------------------------------------------
// gemm4_fused: one block = 64 nodes x all 4 lins; 16 waves = 4 lins x 4 slices.
//   Source staging: layer 0 reads bf16 h; layers 1,2 read f32 S and apply
//   relu(bn(.)) inline (stats of the PREVIOUS layer) -> bf16 LDS.
//   Block only touches its own 64-node rows of S -> no race with lin==3 write.
//   Outputs: lin0 -> K bf16; lin1/2 -> interleaved QV words; lin3 -> f32 S.
// ---------------------------------------------------------------------------
__global__ __launch_bounds__(1024)
void gemm4_fused_kernel(const __hip_bfloat16* __restrict__ hB,
                        const float* __restrict__ Ssrc,       // null for layer 0
                        const float* __restrict__ stp,        // stats prev layer
                        const float* __restrict__ gma,
                        const float* __restrict__ bta,
                        const __hip_bfloat16* __restrict__ wt4, // [4][128o][128i]
                        const float* __restrict__ b4,           // [4][128]
                        __hip_bfloat16* __restrict__ K,
                        unsigned int* __restrict__ QV,          // [n][128] words
                        float* __restrict__ S, int n) {
    __shared__ unsigned short hs[NCH * HDIM];   // 16 KB, linear
    int tid = threadIdx.x;
    int m0 = blockIdx.x * NCH;

    if (Ssrc) {
        // stage 64 x 128 f32 -> bn+relu -> bf16; thread = 8 consecutive ch
        const float4* src = (const float4*)(Ssrc + (size_t)m0 * HDIM);
        float4 v0 = src[tid * 2];
        float4 v1 = src[tid * 2 + 1];
        int c0 = (tid * 8) & 127;
        float invn = 1.f / (float)n;
        float vv[8] = {v0.x, v0.y, v0.z, v0.w, v1.x, v1.y, v1.z, v1.w};
        unsigned int* dst = (unsigned int*)hs + tid * 4;
#pragma unroll
        for (int p = 0; p < 8; p += 2) {
            int c = c0 + p;
            float mA = stp[c] * invn, mB = stp[c + 1] * invn;
            float scA = gma[c] * rsqrtf(stp[128 + c] * invn - mA * mA + BN_EPS);
            float scB = gma[c + 1] * rsqrtf(stp[129 + c] * invn - mB * mB + BN_EPS);
            float shA = bta[c] - mA * scA, shB = bta[c + 1] - mB * scB;
            float rA = fmaxf(fmaf(vv[p], scA, shA), 0.f);
            float rB = fmaxf(fmaf(vv[p + 1], scB, shB), 0.f);
            dst[p >> 1] = pack2bf(rA, rB);
        }
    } else {
        const uint4* src = (const uint4*)((const unsigned short*)hB + (size_t)m0 * HDIM);
        ((uint4*)hs)[tid] = src[tid];
    }

    int wv = tid >> 6;          // 0..15
    int lane = tid & 63;
    int lin = wv >> 2;          // 0..3
    int g2 = wv & 3;            // out-channel slice: channels g2*32 .. +31
    int j = lane & 15;          // node-in-tile (B col, D col)
    int kg = lane >> 4;         // k-group

    const unsigned short* wbase =
        (const unsigned short*)(wt4 + (size_t)lin * HDIM * HDIM);
    bv8 af[2][4];
#pragma unroll
    for (int gs = 0; gs < 2; ++gs)
#pragma unroll
        for (int ks = 0; ks < 4; ++ks)
            af[gs][ks] = *(const bv8*)(wbase +
                (size_t)(g2 * 32 + gs * 16 + j) * HDIM + ks * 32 + kg * 8);

    const float* bl = b4 + lin * HDIM;
    float4 bias0 = *(const float4*)(bl + g2 * 32 + kg * 4);
    float4 bias1 = *(const float4*)(bl + g2 * 32 + 16 + kg * 4);

    __syncthreads();

#pragma unroll
    for (int t4 = 0; t4 < NCH / 16; ++t4) {
        const unsigned short* hrow = hs + (t4 * 16 + j) * HDIM + kg * 8;
        fv4 acc0 = (fv4){0.f, 0.f, 0.f, 0.f};
        fv4 acc1 = (fv4){0.f, 0.f, 0.f, 0.f};
#pragma unroll
        for (int ks = 0; ks < 4; ++ks) {
            bv8 bf = *(const bv8*)(hrow + ks * 32);
            acc0 = __builtin_amdgcn_mfma_f32_16x16x32_bf16(af[0][ks], bf, acc0, 0, 0, 0);
            acc1 = __builtin_amdgcn_mfma_f32_16x16x32_bf16(af[1][ks], bf, acc1, 0, 0, 0);
        }
        int node = m0 + t4 * 16 + j;
        if (node >= n) continue;
        int c0 = g2 * 32 + kg * 4;
        float f0 = acc0.x + bias0.x, f1 = acc0.y + bias0.y;
        float f2 = acc0.z + bias0.z, f3 = acc0.w + bias0.w;
        float f4 = acc1.x + bias1.x, f5 = acc1.y + bias1.y;
        float f6 = acc1.z + bias1.z, f7 = acc1.w + bias1.w;
        if (lin == 3) {
            float* o = S + (size_t)node * HDIM + c0;
            *(float4*)o = (float4){f0, f1, f2, f3};
            *(float4*)(o + 16) = (float4){f4, f5, f6, f7};
        } else if (lin == 0) {
            unsigned short* o = (unsigned short*)K + (size_t)node * HDIM + c0;
            *(ushort4*)o = (ushort4){f2bf(f0), f2bf(f1), f2bf(f2), f2bf(f3)};
            *(ushort4*)(o + 16) = (ushort4){f2bf(f4), f2bf(f5), f2bf(f6), f2bf(f7)};
        } else {
            // interleaved QV: q at even words, v at odd words per ch-pair
            unsigned int* o = QV + (size_t)node * HDIM + c0 + (lin - 1);
            o[0] = pack2bf(f0, f1);
            o[2] = pack2bf(f2, f3);
            o[16] = pack2bf(f4, f5);
            o[18] = pack2bf(f6, f7);
        }
    }
}

// ---------------------------------------------------------------------------
// counting sort of edges by dst: hist -> scan(3 kernels) -> scatter
// ---------------------------------------------------------------------------
__global__ void hist_kernel(const int* __restrict__ ei, int* __restrict__ deg, int e) {
    int i = blockIdx.x * 256 + threadIdx.x;
    if (i < e) atomicAdd(&deg[ei[(size_t)e + i]], 1);
}

__global__ void scan1_kernel(const int* __restrict__ deg, int* __restrict__ incl,
                             int* __restrict__ bsum, int n) {
    __shared__ int tmp[256];
    int i = blockIdx.x * 256 + threadIdx.x;
    int v = (i < n) ? deg[i] : 0;
    tmp[threadIdx.x] = v;
    __syncthreads();
    for (int ofs = 1; ofs < 256; ofs <<= 1) {
        int t = (threadIdx.x >= ofs) ? tmp[threadIdx.x - ofs] : 0;
        __syncthreads();
        tmp[threadIdx.x] += t;
        __syncthreads();
    }
    if (i < n) incl[i] = tmp[threadIdx.x];
    if (threadIdx.x == 255) bsum[blockIdx.x] = tmp[255];
}

__global__ void scan2_kernel(int* __restrict__ bsum, int nb) {
    __shared__ int tmp[256];
    int v = (threadIdx.x < nb) ? bsum[threadIdx.x] : 0;
    tmp[threadIdx.x] = v;
    __syncthreads();
    for (int ofs = 1; ofs < 256; ofs <<= 1) {
        int t = (threadIdx.x >= ofs) ? tmp[threadIdx.x - ofs] : 0;
        __syncthreads();
        tmp[threadIdx.x] += t;
        __syncthreads();
    }
    if (threadIdx.x < nb) bsum[threadIdx.x] = tmp[threadIdx.x] - v;  // exclusive
}

__global__ void scan3_kernel(const int* __restrict__ deg, const int* __restrict__ incl,
                             const int* __restrict__ bsum, int* __restrict__ off,
                             int* __restrict__ cursor, int n, int e) {
    int i = blockIdx.x * 256 + threadIdx.x;
    if (i < n) {
        int ex = incl[i] - deg[i] + bsum[blockIdx.x];
        off[i] = ex;
        cursor[i] = ex;
        if (i == n - 1) off[n] = e;
    }
}

__global__ void scatter_kernel(const int* __restrict__ ei, int* __restrict__ cursor,
                               int* __restrict__ esrc, int e) {
    int i = blockIdx.x * 256 + threadIdx.x;
    if (i < e) {
        int dst = ei[(size_t)e + i];
        int pos = atomicAdd(&cursor[dst], 1);
        esrc[pos] = ei[i];
    }
}

// ---------------------------------------------------------------------------
// agg: S[d] += sum_{j in seg(d)} sigmoid(k[d] + q[src_j]) * v[src_j]
// one wave per dst; ONE uint2 gather per edge (interleaved QV); unroll x4
// ---------------------------------------------------------------------------
__global__ void agg_kernel(const int* __restrict__ off, const int* __restrict__ esrc,
                           const __hip_bfloat16* __restrict__ kb,
                           const unsigned int* __restrict__ QV,
                           float* __restrict__ S, int n) {
    int d = blockIdx.x * 4 + (threadIdx.x >> 6);
    if (d >= n) return;
    int lane = threadIdx.x & 63;
    const uint2* qvw = (const uint2*)QV;   // [node][64] x (qpair, vpair)
    unsigned int kwu = ((const unsigned int*)kb)[(size_t)d * 64 + lane];
    float k0 = bflo(kwu), k1 = bfhi(kwu);
    float a0 = 0.f, a1 = 0.f;

#define EDGE(u)                                               \
    {                                                         \
        float g0 = k0 + bflo(u.x), g1 = k1 + bfhi(u.x);       \
        float e0 = __expf(-g0), e1 = __expf(-g1);             \
        a0 += __fdividef(bflo(u.y), 1.f + e0);                \
        a1 += __fdividef(bfhi(u.y), 1.f + e1);                \
    }

    int j = off[d], s1 = off[d + 1];
    for (; j + 4 <= s1; j += 4) {
        int sA = esrc[j], sB = esrc[j + 1], sC = esrc[j + 2], sD = esrc[j + 3];
        uint2 uA = qvw[(size_t)sA * 64 + lane];
        uint2 uB = qvw[(size_t)sB * 64 + lane];
        uint2 uC = qvw[(size_t)sC * 64 + lane];
        uint2 uD = qvw[(size_t)sD * 64 + lane];
        EDGE(uA); EDGE(uB); EDGE(uC); EDGE(uD);
    }
    for (; j < s1; ++j) {
        int s = esrc[j];
        uint2 u = qvw[(size_t)s * 64 + lane];
        EDGE(u);
    }
#undef EDGE

    float2* sp = (float2*)(S + (size_t)d * HDIM) + lane;
    float2 old = *sp;
    old.x += a0; old.y += a1;
    *sp = old;
}

// ---------------------------------------------------------------------------
// stats: per-channel sum / sumsq of S
// ---------------------------------------------------------------------------
__global__ void stats_kernel(const float* __restrict__ s,
                             float* __restrict__ stats, int n) {
    int c = threadIdx.x & 127, rh = threadIdx.x >> 7;
    int r0 = blockIdx.x * 128;
    int r1 = min(r0 + 128, n);
    float sum = 0.f, sq = 0.f;
    for (int r = r0 + rh; r < r1; r += 2) {
        float v = s[(size_t)r * HDIM + c];
        sum += v;
        sq = fmaf(v, v, sq);
    }
    __shared__ float ls[2][HDIM], lq[2][HDIM];
    ls[rh][c] = sum;
    lq[rh][c] = sq;
    __syncthreads();
    if (rh == 0) {
        atomicAdd(&stats[c], ls[0][c] + ls[1][c]);
        atomicAdd(&stats[HDIM + c], lq[0][c] + lq[1][c]);
    }
}

// ---------------------------------------------------------------------------
// head_bn: out = relu(bn(S)) @ head_w + head_b
// ---------------------------------------------------------------------------
__global__ void head_bn_kernel(const float* __restrict__ S,
                               const float* __restrict__ stats,
                               const float* __restrict__ gamma,
                               const float* __restrict__ beta,
                               const float* __restrict__ w,
                               const float* __restrict__ b,
                               float* __restrict__ out, int n) {
    __shared__ float hsm[8][HDIM];
    float invn = 1.f / (float)n;
    for (int i = threadIdx.x; i < 8 * HDIM; i += 256) {
        int r = i >> 7, c = i & 127;
        int node = blockIdx.x * 8 + r;
        float v = 0.f;
        if (node < n) {
            float mean = stats[c] * invn;
            float var = stats[128 + c] * invn - mean * mean;
            float sc = gamma[c] * rsqrtf(var + BN_EPS);
            float sh = beta[c] - mean * sc;
            v = fmaxf(fmaf(S[(size_t)node * HDIM + c], sc, sh), 0.f);
        }
        hsm[r][c] = v;
    }
    __syncthreads();
    int c = threadIdx.x & 31;
    int ng = threadIdx.x >> 5;
    int node = blockIdx.x * 8 + ng;
    if (node >= n) return;
    float acc = b[c];
#pragma unroll
    for (int k = 0; k < HDIM; ++k)
        acc = fmaf(hsm[ng][k], w[k * OCDIM + c], acc);
    out[(size_t)node * OCDIM + c] = acc;
}

// ---------------------------------------------------------------------------
extern "C" void kernel_launch(void* const* d_in, const int* in_sizes, int n_in,
                              void* d_out, int out_size, void* d_ws, size_t ws_size,
                              hipStream_t stream) {
    const float* x      = (const float*)d_in[0];
    const int*   ei     = (const int*)  d_in[1];
    const float* proj_w = (const float*)d_in[2];
    const float* proj_b = (const float*)d_in[3];
    const float* conv_w = (const float*)d_in[4];  // [3][4][128][128]
    const float* conv_b = (const float*)d_in[5];  // [3][4][128]
    const float* bn_g   = (const float*)d_in[6];
    const float* bn_b   = (const float*)d_in[7];
    const float* head_w = (const float*)d_in[8];
    const float* head_b = (const float*)d_in[9];
    float* out = (float*)d_out;

    int n = in_sizes[0] / ICDIM;   // 50000
    int e = in_sizes[1] / 2;       // 600000

    size_t nh = (size_t)n * HDIM;
    // S f32 | st[768] | h bf16 | K bf16 | QV u32 | Wt | Wp | ints
    size_t need = nh * 4 + 768 * 4 + nh * 2 + nh * 2 + nh * 4
                + (size_t)12 * HDIM * HDIM * 2 + (size_t)HDIM * ICDIM * 2
                + ((size_t)3 * n + (n + 1) + 256 + e) * 4;
    if (ws_size < need) return;

    float* S  = (float*)d_ws;
    float* st = S + nh;                         // 3 x (sum[128], sumsq[128])
    __hip_bfloat16* h = (__hip_bfloat16*)(st + 768);
    __hip_bfloat16* K = h + nh;
    unsigned int* QV = (unsigned int*)(K + nh); // [n][128] words
    __hip_bfloat16* Wt = (__hip_bfloat16*)(QV + nh);     // [3][4][128o][128i]
    __hip_bfloat16* Wp = Wt + (size_t)12 * HDIM * HDIM;  // [128o][64i]

    int* deg    = (int*)(Wp + (size_t)HDIM * ICDIM);
    int* incl   = deg + n;
    int* off    = incl + n;                     // n+1
    int* cursor = off + n + 1;
    int* bsum   = cursor + n;                   // 256
    int* esrc   = bsum + 256;                   // e

    hipMemsetAsync(st, 0, 768 * sizeof(float), stream);
    hipMemsetAsync(deg, 0, (size_t)n * sizeof(int), stream);

    int gb_e = (e + 255) / 256;
    int gb_n = (n + 255) / 256;   // 196 <= 256, scan2 ok

    wconv_kernel<<<12, 256, 0, stream>>>(conv_w, Wt);
    wpconv_kernel<<<1, 256, 0, stream>>>(proj_w, Wp);
    proj_mfma_kernel<<<(n + NCH - 1) / NCH, 256, 0, stream>>>(x, Wp, proj_b, h, n);

    hist_kernel<<<gb_e, 256, 0, stream>>>(ei, deg, e);
    scan1_kernel<<<gb_n, 256, 0, stream>>>(deg, incl, bsum, n);
    scan2_kernel<<<1, 256, 0, stream>>>(bsum, gb_n);
    scan3_kernel<<<gb_n, 256, 0, stream>>>(deg, incl, bsum, off, cursor, n, e);
    scatter_kernel<<<gb_e, 256, 0, stream>>>(ei, cursor, esrc, e);

    int gm = (n + NCH - 1) / NCH;
    for (int l = 0; l < 3; ++l) {
        const float* Ssrc = (l == 0) ? nullptr : S;
        const float* stp  = (l == 0) ? st : st + (size_t)(l - 1) * 256;
        const float* gma  = (l == 0) ? bn_g : bn_g + (size_t)(l - 1) * HDIM;
        const float* bta  = (l == 0) ? bn_b : bn_b + (size_t)(l - 1) * HDIM;
        gemm4_fused_kernel<<<gm, 1024, 0, stream>>>(
            h, Ssrc, stp, gma, bta,
            Wt + (size_t)l * 4 * HDIM * HDIM, conv_b + (size_t)l * 4 * HDIM,
            K, QV, S, n);
        agg_kernel<<<(n + 3) / 4, 256, 0, stream>>>(off, esrc, K, QV, S, n);
        stats_kernel<<<(n + 127) / 128, 256, 0, stream>>>(S, st + l * 256, n);
    }

    head_bn_kernel<<<(n + 7) / 8, 256, 0, stream>>>(
        S, st + 2 * 256, bn_g + 2 * HDIM, bn_b + 2 * HDIM, head_w, head_b, out, n);
}

// Round 10
// 495.886 us; speedup vs baseline: 2.6472x; 1.0021x over previous
//
#include <hip/hip_runtime.h>
#include <hip/hip_bf16.h>
#include <math.h>

#define HDIM 128
#define ICDIM 64
#define OCDIM 32
#define BN_EPS 1e-5f
#define NCH 64   // nodes per gemm block

typedef __attribute__((ext_vector_type(8))) short bv8;   // 8 x bf16 bits (4 VGPR)
typedef __attribute__((ext_vector_type(4))) float fv4;   // MFMA accumulator

static __device__ __forceinline__ unsigned short f2bf(float v) {
    __hip_bfloat16 t = __float2bfloat16(v);
    return *(unsigned short*)&t;
}
static __device__ __forceinline__ float bflo(unsigned int u) {
    union { unsigned int i; float f; } c; c.i = u << 16; return c.f;
}
static __device__ __forceinline__ float bfhi(unsigned int u) {
    union { unsigned int i; float f; } c; c.i = u & 0xffff0000u; return c.f;
}
static __device__ __forceinline__ unsigned int pack2bf(float a, float b) {
    return (unsigned int)f2bf(a) | ((unsigned int)f2bf(b) << 16);
}

// ---------------------------------------------------------------------------
// wprep: blocks 0..11: conv_w [12][128i][128o] f32 -> Wt [12][128o][128i] bf16
//        block  12   : proj_w [64i][128o] f32 -> Wp [128o][64i] bf16
// ---------------------------------------------------------------------------
__global__ void wprep_kernel(const float* __restrict__ conv_w,
                             const float* __restrict__ proj_w,
                             __hip_bfloat16* __restrict__ Wt,
                             __hip_bfloat16* __restrict__ Wp) {
    int mat = blockIdx.x;
    if (mat < 12) {
        const float* s = conv_w + (size_t)mat * HDIM * HDIM;
        __hip_bfloat16* d = Wt + (size_t)mat * HDIM * HDIM;
        for (int idx = threadIdx.x; idx < HDIM * HDIM; idx += 256) {
            int i = idx >> 7, o = idx & 127;
            d[(size_t)o * HDIM + i] = __float2bfloat16(s[idx]);
        }
    } else {
        for (int idx = threadIdx.x; idx < ICDIM * HDIM; idx += 256) {
            int i = idx >> 7, o = idx & 127;
            Wp[(size_t)o * ICDIM + i] = __float2bfloat16(proj_w[idx]);
        }
    }
}

// ---------------------------------------------------------------------------
// proj_mfma: h = relu(x @ proj_w + proj_b) -> bf16 h
//   xs tile XOR-swizzled: byte ^= ((row&7)<<4)  (G4 fix for 128B-stride rows)
// ---------------------------------------------------------------------------
__global__ __launch_bounds__(256)
void proj_mfma_kernel(const float* __restrict__ x,
                      const __hip_bfloat16* __restrict__ wp,  // [128o][64i]
                      const float* __restrict__ b,
                      __hip_bfloat16* __restrict__ h, int n) {
    __shared__ unsigned int xs[NCH * ICDIM / 2];   // 8 KB bf16, [node][64] swizzled
    int tid = threadIdx.x;
    int m0 = blockIdx.x * NCH;

    const float2* xsrc = (const float2*)(x + (size_t)m0 * ICDIM);
    for (int i = tid; i < NCH * ICDIM / 2; i += 256) {
        int node = m0 + (i >> 5);
        float2 v = (node < n) ? xsrc[i] : (float2){0.f, 0.f};
        xs[i ^ (((i >> 5) & 7) << 2)] = pack2bf(v.x, v.y);   // word-level swizzle
    }

    int wv = tid >> 6;          // 0..3  -> out-ch slice wv*32
    int lane = tid & 63;
    int j = lane & 15;          // node-in-tile
    int kg = lane >> 4;         // k-group
    int sw = (j & 7) << 4;      // read-side swizzle (row&7 == j&7)

    bv8 af[2][2];
#pragma unroll
    for (int gs = 0; gs < 2; ++gs)
#pragma unroll
        for (int ks = 0; ks < 2; ++ks)
            af[gs][ks] = *(const bv8*)((const unsigned short*)wp +
                (size_t)(wv * 32 + gs * 16 + j) * ICDIM + ks * 32 + kg * 8);

    float4 bias0 = *(const float4*)(b + wv * 32 + kg * 4);
    float4 bias1 = *(const float4*)(b + wv * 32 + 16 + kg * 4);

    __syncthreads();

#pragma unroll
    for (int t4 = 0; t4 < NCH / 16; ++t4) {
        const char* rowbase = (const char*)xs + (t4 * 16 + j) * (ICDIM * 2);
        fv4 acc0 = (fv4){0.f, 0.f, 0.f, 0.f};
        fv4 acc1 = (fv4){0.f, 0.f, 0.f, 0.f};
#pragma unroll
        for (int ks = 0; ks < 2; ++ks) {
            bv8 bf = *(const bv8*)(rowbase + ((kg * 16 + ks * 64) ^ sw));
            acc0 = __builtin_amdgcn_mfma_f32_16x16x32_bf16(af[0][ks], bf, acc0, 0, 0, 0);
            acc1 = __builtin_amdgcn_mfma_f32_16x16x32_bf16(af[1][ks], bf, acc1, 0, 0, 0);
        }
        int node = m0 + t4 * 16 + j;
        if (node < n) {
            unsigned short* o =
                (unsigned short*)h + (size_t)node * HDIM + wv * 32 + kg * 4;
            ushort4 r0, r1;
            r0.x = f2bf(fmaxf(acc0.x + bias0.x, 0.f));
            r0.y = f2bf(fmaxf(acc0.y + bias0.y, 0.f));
            r0.z = f2bf(fmaxf(acc0.z + bias0.z, 0.f));
            r0.w = f2bf(fmaxf(acc0.w + bias0.w, 0.f));
            r1.x = f2bf(fmaxf(acc1.x + bias1.x, 0.f));
            r1.y = f2bf(fmaxf(acc1.y + bias1.y, 0.f));
            r1.z = f2bf(fmaxf(acc1.z + bias1.z, 0.f));
            r1.w = f2bf(fmaxf(acc1.w + bias1.w, 0.f));
            *(ushort4*)o = r0;
            *(ushort4*)(o + 16) = r1;
        }
    }
}

// ---------------------------------------------------------------------------
// gemm4_fused: one block = 64 nodes x all 4 lins; 16 waves = 4 lins x 4 slices.
//   hs tile XOR-swizzled (byte ^= (row&7)<<4) on both write and read:
//   removes the 16-way ds_read_b128 bank conflict of linear 256B rows.
// ---------------------------------------------------------------------------
__global__ __launch_bounds__(1024)
void gemm4_fused_kernel(const __hip_bfloat16* __restrict__ hB,
                        const float* __restrict__ Ssrc,       // null for layer 0
                        const float* __restrict__ stp,        // stats prev layer
                        const float* __restrict__ gma,
                        const float* __restrict__ bta,
                        const __hip_bfloat16* __restrict__ wt4, // [4][128o][128i]
                        const float* __restrict__ b4,           // [4][128]
                        __hip_bfloat16* __restrict__ K,
                        unsigned int* __restrict__ QV,          // [n][128] words
                        float* __restrict__ S, int n) {
    __shared__ unsigned short hs[NCH * HDIM];   // 16 KB, swizzled
    int tid = threadIdx.x;
    int m0 = blockIdx.x * NCH;
    int wsw = ((tid >> 4) & 7) << 4;            // write-side swizzle (row = tid>>4)

    if (Ssrc) {
        // stage 64 x 128 f32 -> bn+relu -> bf16; thread = 8 consecutive ch
        const float4* src = (const float4*)(Ssrc + (size_t)m0 * HDIM);
        float4 v0 = src[tid * 2];
        float4 v1 = src[tid * 2 + 1];
        int c0 = (tid * 8) & 127;
        float invn = 1.f / (float)n;
        float vv[8] = {v0.x, v0.y, v0.z, v0.w, v1.x, v1.y, v1.z, v1.w};
        unsigned int* dst = (unsigned int*)((char*)hs + ((tid * 16) ^ wsw));
#pragma unroll
        for (int p = 0; p < 8; p += 2) {
            int c = c0 + p;
            float mA = stp[c] * invn, mB = stp[c + 1] * invn;
            float scA = gma[c] * rsqrtf(stp[128 + c] * invn - mA * mA + BN_EPS);
            float scB = gma[c + 1] * rsqrtf(stp[129 + c] * invn - mB * mB + BN_EPS);
            float shA = bta[c] - mA * scA, shB = bta[c + 1] - mB * scB;
            float rA = fmaxf(fmaf(vv[p], scA, shA), 0.f);
            float rB = fmaxf(fmaf(vv[p + 1], scB, shB), 0.f);
            dst[p >> 1] = pack2bf(rA, rB);
        }
    } else {
        const uint4* src = (const uint4*)((const unsigned short*)hB + (size_t)m0 * HDIM);
        *(uint4*)((char*)hs + ((tid * 16) ^ wsw)) = src[tid];
    }

    int wv = tid >> 6;          // 0..15
    int lane = tid & 63;
    int lin = wv >> 2;          // 0..3
    int g2 = wv & 3;            // out-channel slice: channels g2*32 .. +31
    int j = lane & 15;          // node-in-tile (B col, D col)
    int kg = lane >> 4;         // k-group
    int sw = (j & 7) << 4;      // read-side swizzle (row&7 == j&7)

    const unsigned short* wbase =
        (const unsigned short*)(wt4 + (size_t)lin * HDIM * HDIM);
    bv8 af[2][4];
#pragma unroll
    for (int gs = 0; gs < 2; ++gs)
#pragma unroll
        for (int ks = 0; ks < 4; ++ks)
            af[gs][ks] = *(const bv8*)(wbase +
                (size_t)(g2 * 32 + gs * 16 + j) * HDIM + ks * 32 + kg * 8);

    const float* bl = b4 + lin * HDIM;
    float4 bias0 = *(const float4*)(bl + g2 * 32 + kg * 4);
    float4 bias1 = *(const float4*)(bl + g2 * 32 + 16 + kg * 4);

    __syncthreads();

#pragma unroll
    for (int t4 = 0; t4 < NCH / 16; ++t4) {
        const char* rowbase = (const char*)hs + (t4 * 16 + j) * (HDIM * 2);
        fv4 acc0 = (fv4){0.f, 0.f, 0.f, 0.f};
        fv4 acc1 = (fv4){0.f, 0.f, 0.f, 0.f};
#pragma unroll
        for (int ks = 0; ks < 4; ++ks) {
            bv8 bf = *(const bv8*)(rowbase + ((kg * 16 + ks * 64) ^ sw));
            acc0 = __builtin_amdgcn_mfma_f32_16x16x32_bf16(af[0][ks], bf, acc0, 0, 0, 0);
            acc1 = __builtin_amdgcn_mfma_f32_16x16x32_bf16(af[1][ks], bf, acc1, 0, 0, 0);
        }
        int node = m0 + t4 * 16 + j;
        if (node >= n) continue;
        int c0 = g2 * 32 + kg * 4;
        float f0 = acc0.x + bias0.x, f1 = acc0.y + bias0.y;
        float f2 = acc0.z + bias0.z, f3 = acc0.w + bias0.w;
        float f4 = acc1.x + bias1.x, f5 = acc1.y + bias1.y;
        float f6 = acc1.z + bias1.z, f7 = acc1.w + bias1.w;
        if (lin == 3) {
            float* o = S + (size_t)node * HDIM + c0;
            *(float4*)o = (float4){f0, f1, f2, f3};
            *(float4*)(o + 16) = (float4){f4, f5, f6, f7};
        } else if (lin == 0) {
            unsigned short* o = (unsigned short*)K + (size_t)node * HDIM + c0;
            *(ushort4*)o = (ushort4){f2bf(f0), f2bf(f1), f2bf(f2), f2bf(f3)};
            *(ushort4*)(o + 16) = (ushort4){f2bf(f4), f2bf(f5), f2bf(f6), f2bf(f7)};
        } else {
            // interleaved QV: q at even words, v at odd words per ch-pair
            unsigned int* o = QV + (size_t)node * HDIM + c0 + (lin - 1);
            o[0] = pack2bf(f0, f1);
            o[2] = pack2bf(f2, f3);
            o[16] = pack2bf(f4, f5);
            o[18] = pack2bf(f6, f7);
        }
    }
}

// ---------------------------------------------------------------------------
// counting sort of edges by dst: hist -> scan(3 kernels) -> scatter
// ---------------------------------------------------------------------------
__global__ void hist_kernel(const int* __restrict__ ei, int* __restrict__ deg, int e) {
    int i = blockIdx.x * 256 + threadIdx.x;
    if (i < e) atomicAdd(&deg[ei[(size_t)e + i]], 1);
}

__global__ void scan1_kernel(const int* __restrict__ deg, int* __restrict__ incl,
                             int* __restrict__ bsum, int n) {
    __shared__ int tmp[256];
    int i = blockIdx.x * 256 + threadIdx.x;
    int v = (i < n) ? deg[i] : 0;
    tmp[threadIdx.x] = v;
    __syncthreads();
    for (int ofs = 1; ofs < 256; ofs <<= 1) {
        int t = (threadIdx.x >= ofs) ? tmp[threadIdx.x - ofs] : 0;
        __syncthreads();
        tmp[threadIdx.x] += t;
        __syncthreads();
    }
    if (i < n) incl[i] = tmp[threadIdx.x];
    if (threadIdx.x == 255) bsum[blockIdx.x] = tmp[255];
}

__global__ void scan2_kernel(int* __restrict__ bsum, int nb) {
    __shared__ int tmp[256];
    int v = (threadIdx.x < nb) ? bsum[threadIdx.x] : 0;
    tmp[threadIdx.x] = v;
    __syncthreads();
    for (int ofs = 1; ofs < 256; ofs <<= 1) {
        int t = (threadIdx.x >= ofs) ? tmp[threadIdx.x - ofs] : 0;
        __syncthreads();
        tmp[threadIdx.x] += t;
        __syncthreads();
    }
    if (threadIdx.x < nb) bsum[threadIdx.x] = tmp[threadIdx.x] - v;  // exclusive
}

__global__ void scan3_kernel(const int* __restrict__ deg, const int* __restrict__ incl,
                             const int* __restrict__ bsum, int* __restrict__ off,
                             int* __restrict__ cursor, int n, int e) {
    int i = blockIdx.x * 256 + threadIdx.x;
    if (i < n) {
        int ex = incl[i] - deg[i] + bsum[blockIdx.x];
        off[i] = ex;
        cursor[i] = ex;
        if (i == n - 1) off[n] = e;
    }
}

__global__ void scatter_kernel(const int* __restrict__ ei, int* __restrict__ cursor,
                               int* __restrict__ esrc, int e) {
    int i = blockIdx.x * 256 + threadIdx.x;
    if (i < e) {
        int dst = ei[(size_t)e + i];
        int pos = atomicAdd(&cursor[dst], 1);
        esrc[pos] = ei[i];
    }
}

// ---------------------------------------------------------------------------
// agg: S[d] += sum_{j in seg(d)} sigmoid(k[d] + q[src_j]) * v[src_j]
// one wave per dst; one uint2 gather per edge; depth-2 software pipeline
// ---------------------------------------------------------------------------
__global__ void agg_kernel(const int* __restrict__ off, const int* __restrict__ esrc,
                           const __hip_bfloat16* __restrict__ kb,
                           const unsigned int* __restrict__ QV,
                           float* __restrict__ S, int n) {
    int d = blockIdx.x * 4 + (threadIdx.x >> 6);
    if (d >= n) return;
    int lane = threadIdx.x & 63;
    const uint2* qvw = (const uint2*)QV;   // [node][64] x (qpair, vpair)
    unsigned int kwu = ((const unsigned int*)kb)[(size_t)d * 64 + lane];
    float k0 = bflo(kwu), k1 = bfhi(kwu);
    float a0 = 0.f, a1 = 0.f;

#define EDGE(u)                                               \
    {                                                         \
        float g0 = k0 + bflo(u.x), g1 = k1 + bfhi(u.x);       \
        float e0 = __expf(-g0), e1 = __expf(-g1);             \
        a0 += __fdividef(bflo(u.y), 1.f + e0);                \
        a1 += __fdividef(bfhi(u.y), 1.f + e1);                \
    }

    int j0 = off[d], s1 = off[d + 1];
    int nb = (s1 - j0) >> 2;     // full 4-edge batches
    uint2 cu0, cu1, cu2, cu3;
    if (nb > 0) {
        int sA = esrc[j0], sB = esrc[j0 + 1], sC = esrc[j0 + 2], sD = esrc[j0 + 3];
        cu0 = qvw[(size_t)sA * 64 + lane];
        cu1 = qvw[(size_t)sB * 64 + lane];
        cu2 = qvw[(size_t)sC * 64 + lane];
        cu3 = qvw[(size_t)sD * 64 + lane];
    }
    for (int b = 1; b < nb; ++b) {
        int jn = j0 + b * 4;
        int sA = esrc[jn], sB = esrc[jn + 1], sC = esrc[jn + 2], sD = esrc[jn + 3];
        uint2 nu0 = qvw[(size_t)sA * 64 + lane];
        uint2 nu1 = qvw[(size_t)sB * 64 + lane];
        uint2 nu2 = qvw[(size_t)sC * 64 + lane];
        uint2 nu3 = qvw[(size_t)sD * 64 + lane];
        EDGE(cu0); EDGE(cu1); EDGE(cu2); EDGE(cu3);
        cu0 = nu0; cu1 = nu1; cu2 = nu2; cu3 = nu3;
    }
    if (nb > 0) { EDGE(cu0); EDGE(cu1); EDGE(cu2); EDGE(cu3); }
    for (int j = j0 + nb * 4; j < s1; ++j) {
        int s = esrc[j];
        uint2 u = qvw[(size_t)s * 64 + lane];
        EDGE(u);
    }
#undef EDGE

    float2* sp = (float2*)(S + (size_t)d * HDIM) + lane;
    float2 old = *sp;
    old.x += a0; old.y += a1;
    *sp = old;
}

// ---------------------------------------------------------------------------
// stats: per-channel sum / sumsq of S
// ---------------------------------------------------------------------------
__global__ void stats_kernel(const float* __restrict__ s,
                             float* __restrict__ stats, int n) {
    int c = threadIdx.x & 127, rh = threadIdx.x >> 7;
    int r0 = blockIdx.x * 128;
    int r1 = min(r0 + 128, n);
    float sum = 0.f, sq = 0.f;
    for (int r = r0 + rh; r < r1; r += 2) {
        float v = s[(size_t)r * HDIM + c];
        sum += v;
        sq = fmaf(v, v, sq);
    }
    __shared__ float ls[2][HDIM], lq[2][HDIM];
    ls[rh][c] = sum;
    lq[rh][c] = sq;
    __syncthreads();
    if (rh == 0) {
        atomicAdd(&stats[c], ls[0][c] + ls[1][c]);
        atomicAdd(&stats[HDIM + c], lq[0][c] + lq[1][c]);
    }
}

// ---------------------------------------------------------------------------
// head_bn: out = relu(bn(S)) @ head_w + head_b
// ---------------------------------------------------------------------------
__global__ void head_bn_kernel(const float* __restrict__ S,
                               const float* __restrict__ stats,
                               const float* __restrict__ gamma,
                               const float* __restrict__ beta,
                               const float* __restrict__ w,
                               const float* __restrict__ b,
                               float* __restrict__ out, int n) {
    __shared__ float hsm[8][HDIM];
    float invn = 1.f / (float)n;
    for (int i = threadIdx.x; i < 8 * HDIM; i += 256) {
        int r = i >> 7, c = i & 127;
        int node = blockIdx.x * 8 + r;
        float v = 0.f;
        if (node < n) {
            float mean = stats[c] * invn;
            float var = stats[128 + c] * invn - mean * mean;
            float sc = gamma[c] * rsqrtf(var + BN_EPS);
            float sh = beta[c] - mean * sc;
            v = fmaxf(fmaf(S[(size_t)node * HDIM + c], sc, sh), 0.f);
        }
        hsm[r][c] = v;
    }
    __syncthreads();
    int c = threadIdx.x & 31;
    int ng = threadIdx.x >> 5;
    int node = blockIdx.x * 8 + ng;
    if (node >= n) return;
    float acc = b[c];
#pragma unroll
    for (int k = 0; k < HDIM; ++k)
        acc = fmaf(hsm[ng][k], w[k * OCDIM + c], acc);
    out[(size_t)node * OCDIM + c] = acc;
}

// ---------------------------------------------------------------------------
extern "C" void kernel_launch(void* const* d_in, const int* in_sizes, int n_in,
                              void* d_out, int out_size, void* d_ws, size_t ws_size,
                              hipStream_t stream) {
    const float* x      = (const float*)d_in[0];
    const int*   ei     = (const int*)  d_in[1];
    const float* proj_w = (const float*)d_in[2];
    const float* proj_b = (const float*)d_in[3];
    const float* conv_w = (const float*)d_in[4];  // [3][4][128][128]
    const float* conv_b = (const float*)d_in[5];  // [3][4][128]
    const float* bn_g   = (const float*)d_in[6];
    const float* bn_b   = (const float*)d_in[7];
    const float* head_w = (const float*)d_in[8];
    const float* head_b = (const float*)d_in[9];
    float* out = (float*)d_out;

    int n = in_sizes[0] / ICDIM;   // 50000
    int e = in_sizes[1] / 2;       // 600000

    size_t nh = (size_t)n * HDIM;
    // S f32 | st[768] | h bf16 | K bf16 | QV u32 | Wt | Wp | ints
    size_t need = nh * 4 + 768 * 4 + nh * 2 + nh * 2 + nh * 4
                + (size_t)12 * HDIM * HDIM * 2 + (size_t)HDIM * ICDIM * 2
                + ((size_t)3 * n + (n + 1) + 256 + e) * 4;
    if (ws_size < need) return;

    float* S  = (float*)d_ws;
    float* st = S + nh;                         // 3 x (sum[128], sumsq[128])
    __hip_bfloat16* h = (__hip_bfloat16*)(st + 768);
    __hip_bfloat16* K = h + nh;
    unsigned int* QV = (unsigned int*)(K + nh); // [n][128] words
    __hip_bfloat16* Wt = (__hip_bfloat16*)(QV + nh);     // [3][4][128o][128i]
    __hip_bfloat16* Wp = Wt + (size_t)12 * HDIM * HDIM;  // [128o][64i]

    int* deg    = (int*)(Wp + (size_t)HDIM * ICDIM);
    int* incl   = deg + n;
    int* off    = incl + n;                     // n+1
    int* cursor = off + n + 1;
    int* bsum   = cursor + n;                   // 256
    int* esrc   = bsum + 256;                   // e

    hipMemsetAsync(st, 0, 768 * sizeof(float), stream);
    hipMemsetAsync(deg, 0, (size_t)n * sizeof(int), stream);

    int gb_e = (e + 255) / 256;
    int gb_n = (n + 255) / 256;   // 196 <= 256, scan2 ok

    wprep_kernel<<<13, 256, 0, stream>>>(conv_w, proj_w, Wt, Wp);
    proj_mfma_kernel<<<(n + NCH - 1) / NCH, 256, 0, stream>>>(x, Wp, proj_b, h, n);

    hist_kernel<<<gb_e, 256, 0, stream>>>(ei, deg, e);
    scan1_kernel<<<gb_n, 256, 0, stream>>>(deg, incl, bsum, n);
    scan2_kernel<<<1, 256, 0, stream>>>(bsum, gb_n);
    scan3_kernel<<<gb_n, 256, 0, stream>>>(deg, incl, bsum, off, cursor, n, e);
    scatter_kernel<<<gb_e, 256, 0, stream>>>(ei, cursor, esrc, e);

    int gm = (n + NCH - 1) / NCH;
    for (int l = 0; l < 3; ++l) {
        const float* Ssrc = (l == 0) ? nullptr : S;
        const float* stp  = (l == 0) ? st : st + (size_t)(l - 1) * 256;
        const float* gma  = (l == 0) ? bn_g : bn_g + (size_t)(l - 1) * HDIM;
        const float* bta  = (l == 0) ? bn_b : bn_b + (size_t)(l - 1) * HDIM;
        gemm4_fused_kernel<<<gm, 1024, 0, stream>>>(
            h, Ssrc, stp, gma, bta,
            Wt + (size_t)l * 4 * HDIM * HDIM, conv_b + (size_t)l * 4 * HDIM,
            K, QV, S, n);
        agg_kernel<<<(n + 3) / 4, 256, 0, stream>>>(off, esrc, K, QV, S, n);
        stats_kernel<<<(n + 127) / 128, 256, 0, stream>>>(S, st + l * 256, n);
    }

    head_bn_kernel<<<(n + 7) / 8, 256, 0, stream>>>(
        S, st + 2 * 256, bn_g + 2 * HDIM, bn_b + 2 * HDIM, head_w, head_b, out, n);
}

// Round 11
// 467.809 us; speedup vs baseline: 2.8061x; 1.0600x over previous
//
#include <hip/hip_runtime.h>
#include <hip/hip_bf16.h>
#include <math.h>

#define HDIM 128
#define ICDIM 64
#define OCDIM 32
#define BN_EPS 1e-5f
#define NCH 64   // nodes per gemm block

typedef __attribute__((ext_vector_type(8))) short bv8;   // 8 x bf16 bits (4 VGPR)
typedef __attribute__((ext_vector_type(4))) float fv4;   // MFMA accumulator

static __device__ __forceinline__ unsigned short f2bf(float v) {
    __hip_bfloat16 t = __float2bfloat16(v);
    return *(unsigned short*)&t;
}
static __device__ __forceinline__ float bflo(unsigned int u) {
    union { unsigned int i; float f; } c; c.i = u << 16; return c.f;
}
static __device__ __forceinline__ float bfhi(unsigned int u) {
    union { unsigned int i; float f; } c; c.i = u & 0xffff0000u; return c.f;
}
static __device__ __forceinline__ unsigned int pack2bf(float a, float b) {
    return (unsigned int)f2bf(a) | ((unsigned int)f2bf(b) << 16);
}

// ---------------------------------------------------------------------------
// wprep: blocks 0..11: conv_w [12][128i][128o] f32 -> Wt [12][128o][128i] bf16
//        block  12   : proj_w [64i][128o] f32 -> Wp [128o][64i] bf16
// ---------------------------------------------------------------------------
__global__ void wprep_kernel(const float* __restrict__ conv_w,
                             const float* __restrict__ proj_w,
                             __hip_bfloat16* __restrict__ Wt,
                             __hip_bfloat16* __restrict__ Wp) {
    int mat = blockIdx.x;
    if (mat < 12) {
        const float* s = conv_w + (size_t)mat * HDIM * HDIM;
        __hip_bfloat16* d = Wt + (size_t)mat * HDIM * HDIM;
        for (int idx = threadIdx.x; idx < HDIM * HDIM; idx += 256) {
            int i = idx >> 7, o = idx & 127;
            d[(size_t)o * HDIM + i] = __float2bfloat16(s[idx]);
        }
    } else {
        for (int idx = threadIdx.x; idx < ICDIM * HDIM; idx += 256) {
            int i = idx >> 7, o = idx & 127;
            Wp[(size_t)o * ICDIM + i] = __float2bfloat16(proj_w[idx]);
        }
    }
}

// ---------------------------------------------------------------------------
// proj_mfma: h = relu(x @ proj_w + proj_b) -> bf16 h   (xs XOR-swizzled)
// ---------------------------------------------------------------------------
__global__ __launch_bounds__(256)
void proj_mfma_kernel(const float* __restrict__ x,
                      const __hip_bfloat16* __restrict__ wp,  // [128o][64i]
                      const float* __restrict__ b,
                      __hip_bfloat16* __restrict__ h, int n) {
    __shared__ unsigned int xs[NCH * ICDIM / 2];   // 8 KB bf16, [node][64] swizzled
    int tid = threadIdx.x;
    int m0 = blockIdx.x * NCH;

    const float2* xsrc = (const float2*)(x + (size_t)m0 * ICDIM);
    for (int i = tid; i < NCH * ICDIM / 2; i += 256) {
        int node = m0 + (i >> 5);
        float2 v = (node < n) ? xsrc[i] : (float2){0.f, 0.f};
        xs[i ^ (((i >> 5) & 7) << 2)] = pack2bf(v.x, v.y);   // word-level swizzle
    }

    int wv = tid >> 6;          // 0..3  -> out-ch slice wv*32
    int lane = tid & 63;
    int j = lane & 15;          // node-in-tile
    int kg = lane >> 4;         // k-group
    int sw = (j & 7) << 4;      // read-side swizzle (row&7 == j&7)

    bv8 af[2][2];
#pragma unroll
    for (int gs = 0; gs < 2; ++gs)
#pragma unroll
        for (int ks = 0; ks < 2; ++ks)
            af[gs][ks] = *(const bv8*)((const unsigned short*)wp +
                (size_t)(wv * 32 + gs * 16 + j) * ICDIM + ks * 32 + kg * 8);

    float4 bias0 = *(const float4*)(b + wv * 32 + kg * 4);
    float4 bias1 = *(const float4*)(b + wv * 32 + 16 + kg * 4);

    __syncthreads();

#pragma unroll
    for (int t4 = 0; t4 < NCH / 16; ++t4) {
        const char* rowbase = (const char*)xs + (t4 * 16 + j) * (ICDIM * 2);
        fv4 acc0 = (fv4){0.f, 0.f, 0.f, 0.f};
        fv4 acc1 = (fv4){0.f, 0.f, 0.f, 0.f};
#pragma unroll
        for (int ks = 0; ks < 2; ++ks) {
            bv8 bf = *(const bv8*)(rowbase + ((kg * 16 + ks * 64) ^ sw));
            acc0 = __builtin_amdgcn_mfma_f32_16x16x32_bf16(af[0][ks], bf, acc0, 0, 0, 0);
            acc1 = __builtin_amdgcn_mfma_f32_16x16x32_bf16(af[1][ks], bf, acc1, 0, 0, 0);
        }
        int node = m0 + t4 * 16 + j;
        if (node < n) {
            unsigned short* o =
                (unsigned short*)h + (size_t)node * HDIM + wv * 32 + kg * 4;
            ushort4 r0, r1;
            r0.x = f2bf(fmaxf(acc0.x + bias0.x, 0.f));
            r0.y = f2bf(fmaxf(acc0.y + bias0.y, 0.f));
            r0.z = f2bf(fmaxf(acc0.z + bias0.z, 0.f));
            r0.w = f2bf(fmaxf(acc0.w + bias0.w, 0.f));
            r1.x = f2bf(fmaxf(acc1.x + bias1.x, 0.f));
            r1.y = f2bf(fmaxf(acc1.y + bias1.y, 0.f));
            r1.z = f2bf(fmaxf(acc1.z + bias1.z, 0.f));
            r1.w = f2bf(fmaxf(acc1.w + bias1.w, 0.f));
            *(ushort4*)o = r0;
            *(ushort4*)(o + 16) = r1;
        }
    }
}

// ---------------------------------------------------------------------------
// gemm4_fused: one block = 64 nodes x all 4 lins; 16 waves = 4 lins x 4 slices.
//   QV layout (8B granular): node row = 32 chunks x 16B;
//   chunk c = { q[4c..4c+3] bf16x4 | v[4c..4c+3] bf16x4 }.
// ---------------------------------------------------------------------------
__global__ __launch_bounds__(1024)
void gemm4_fused_kernel(const __hip_bfloat16* __restrict__ hB,
                        const float* __restrict__ Ssrc,       // null for layer 0
                        const float* __restrict__ stp,        // stats prev layer
                        const float* __restrict__ gma,
                        const float* __restrict__ bta,
                        const __hip_bfloat16* __restrict__ wt4, // [4][128o][128i]
                        const float* __restrict__ b4,           // [4][128]
                        __hip_bfloat16* __restrict__ K,
                        unsigned int* __restrict__ QV,          // [n][128] words
                        float* __restrict__ S, int n) {
    __shared__ unsigned short hs[NCH * HDIM];   // 16 KB, swizzled
    int tid = threadIdx.x;
    int m0 = blockIdx.x * NCH;
    int wsw = ((tid >> 4) & 7) << 4;            // write-side swizzle (row = tid>>4)

    if (Ssrc) {
        // stage 64 x 128 f32 -> bn+relu -> bf16; thread = 8 consecutive ch
        const float4* src = (const float4*)(Ssrc + (size_t)m0 * HDIM);
        float4 v0 = src[tid * 2];
        float4 v1 = src[tid * 2 + 1];
        int c0 = (tid * 8) & 127;
        float invn = 1.f / (float)n;
        float vv[8] = {v0.x, v0.y, v0.z, v0.w, v1.x, v1.y, v1.z, v1.w};
        unsigned int* dst = (unsigned int*)((char*)hs + ((tid * 16) ^ wsw));
#pragma unroll
        for (int p = 0; p < 8; p += 2) {
            int c = c0 + p;
            float mA = stp[c] * invn, mB = stp[c + 1] * invn;
            float scA = gma[c] * rsqrtf(stp[128 + c] * invn - mA * mA + BN_EPS);
            float scB = gma[c + 1] * rsqrtf(stp[129 + c] * invn - mB * mB + BN_EPS);
            float shA = bta[c] - mA * scA, shB = bta[c + 1] - mB * scB;
            float rA = fmaxf(fmaf(vv[p], scA, shA), 0.f);
            float rB = fmaxf(fmaf(vv[p + 1], scB, shB), 0.f);
            dst[p >> 1] = pack2bf(rA, rB);
        }
    } else {
        const uint4* src = (const uint4*)((const unsigned short*)hB + (size_t)m0 * HDIM);
        *(uint4*)((char*)hs + ((tid * 16) ^ wsw)) = src[tid];
    }

    int wv = tid >> 6;          // 0..15
    int lane = tid & 63;
    int lin = wv >> 2;          // 0..3
    int g2 = wv & 3;            // out-channel slice: channels g2*32 .. +31
    int j = lane & 15;          // node-in-tile (B col, D col)
    int kg = lane >> 4;         // k-group
    int sw = (j & 7) << 4;      // read-side swizzle (row&7 == j&7)

    const unsigned short* wbase =
        (const unsigned short*)(wt4 + (size_t)lin * HDIM * HDIM);
    bv8 af[2][4];
#pragma unroll
    for (int gs = 0; gs < 2; ++gs)
#pragma unroll
        for (int ks = 0; ks < 4; ++ks)
            af[gs][ks] = *(const bv8*)(wbase +
                (size_t)(g2 * 32 + gs * 16 + j) * HDIM + ks * 32 + kg * 8);

    const float* bl = b4 + lin * HDIM;
    float4 bias0 = *(const float4*)(bl + g2 * 32 + kg * 4);
    float4 bias1 = *(const float4*)(bl + g2 * 32 + 16 + kg * 4);

    __syncthreads();

#pragma unroll
    for (int t4 = 0; t4 < NCH / 16; ++t4) {
        const char* rowbase = (const char*)hs + (t4 * 16 + j) * (HDIM * 2);
        fv4 acc0 = (fv4){0.f, 0.f, 0.f, 0.f};
        fv4 acc1 = (fv4){0.f, 0.f, 0.f, 0.f};
#pragma unroll
        for (int ks = 0; ks < 4; ++ks) {
            bv8 bf = *(const bv8*)(rowbase + ((kg * 16 + ks * 64) ^ sw));
            acc0 = __builtin_amdgcn_mfma_f32_16x16x32_bf16(af[0][ks], bf, acc0, 0, 0, 0);
            acc1 = __builtin_amdgcn_mfma_f32_16x16x32_bf16(af[1][ks], bf, acc1, 0, 0, 0);
        }
        int node = m0 + t4 * 16 + j;
        if (node >= n) continue;
        int c0 = g2 * 32 + kg * 4;
        float f0 = acc0.x + bias0.x, f1 = acc0.y + bias0.y;
        float f2 = acc0.z + bias0.z, f3 = acc0.w + bias0.w;
        float f4 = acc1.x + bias1.x, f5 = acc1.y + bias1.y;
        float f6 = acc1.z + bias1.z, f7 = acc1.w + bias1.w;
        if (lin == 3) {
            float* o = S + (size_t)node * HDIM + c0;
            *(float4*)o = (float4){f0, f1, f2, f3};
            *(float4*)(o + 16) = (float4){f4, f5, f6, f7};
        } else if (lin == 0) {
            unsigned short* o = (unsigned short*)K + (size_t)node * HDIM + c0;
            *(ushort4*)o = (ushort4){f2bf(f0), f2bf(f1), f2bf(f2), f2bf(f3)};
            *(ushort4*)(o + 16) = (ushort4){f2bf(f4), f2bf(f5), f2bf(f6), f2bf(f7)};
        } else {
            // 8B-granular QV: chunk c0/4 at ushort 2*c0; q at +0, v at +4
            unsigned short* o = (unsigned short*)QV + (size_t)node * 256 + 2 * c0
                              + ((lin == 2) ? 4 : 0);
            *(ushort4*)o = (ushort4){f2bf(f0), f2bf(f1), f2bf(f2), f2bf(f3)};
            *(ushort4*)(o + 32) = (ushort4){f2bf(f4), f2bf(f5), f2bf(f6), f2bf(f7)};
        }
    }
}

// ---------------------------------------------------------------------------
// counting sort of edges by dst: hist -> scan1 -> scan23 -> scatter
// ---------------------------------------------------------------------------
__global__ void hist_kernel(const int* __restrict__ ei, int* __restrict__ deg, int e) {
    int i = blockIdx.x * 256 + threadIdx.x;
    if (i < e) atomicAdd(&deg[ei[(size_t)e + i]], 1);
}

__global__ void scan1_kernel(const int* __restrict__ deg, int* __restrict__ incl,
                             int* __restrict__ bsum, int n) {
    __shared__ int tmp[256];
    int i = blockIdx.x * 256 + threadIdx.x;
    int v = (i < n) ? deg[i] : 0;
    tmp[threadIdx.x] = v;
    __syncthreads();
    for (int ofs = 1; ofs < 256; ofs <<= 1) {
        int t = (threadIdx.x >= ofs) ? tmp[threadIdx.x - ofs] : 0;
        __syncthreads();
        tmp[threadIdx.x] += t;
        __syncthreads();
    }
    if (i < n) incl[i] = tmp[threadIdx.x];
    if (threadIdx.x == 255) bsum[blockIdx.x] = tmp[255];
}

// scan23: every block scans bsum[0..nb) redundantly in LDS, then applies its
// own exclusive prefix to produce off/cursor. Replaces scan2 + scan3.
__global__ void scan23_kernel(const int* __restrict__ deg, const int* __restrict__ incl,
                              const int* __restrict__ bsum, int* __restrict__ off,
                              int* __restrict__ cursor, int n, int e, int nb) {
    __shared__ int tmp[256];
    int t = threadIdx.x;
    tmp[t] = (t < nb) ? bsum[t] : 0;
    __syncthreads();
    for (int ofs = 1; ofs < 256; ofs <<= 1) {
        int a = (t >= ofs) ? tmp[t - ofs] : 0;
        __syncthreads();
        tmp[t] += a;
        __syncthreads();
    }
    int pre = (blockIdx.x == 0) ? 0 : tmp[blockIdx.x - 1];
    int i = blockIdx.x * 256 + t;
    if (i < n) {
        int ex = incl[i] - deg[i] + pre;
        off[i] = ex;
        cursor[i] = ex;
        if (i == n - 1) off[n] = e;
    }
}

__global__ void scatter_kernel(const int* __restrict__ ei, int* __restrict__ cursor,
                               int* __restrict__ esrc, int e) {
    int i = blockIdx.x * 256 + threadIdx.x;
    if (i < e) {
        int dst = ei[(size_t)e + i];
        int pos = atomicAdd(&cursor[dst], 1);
        esrc[pos] = ei[i];
    }
}

// ---------------------------------------------------------------------------
// agg: S[d] += sum_{j in seg(d)} sigmoid(k[d] + q[src_j]) * v[src_j]
// one wave per dst; lane = (edge-parity, 4-ch chunk); one uint4 gather
// serves 2 edges; halves combined via shfl_xor(32).
// ---------------------------------------------------------------------------
__global__ void agg_kernel(const int* __restrict__ off, const int* __restrict__ esrc,
                           const __hip_bfloat16* __restrict__ kb,
                           const unsigned int* __restrict__ QV,
                           float* __restrict__ S, int n) {
    int d = blockIdx.x * 4 + (threadIdx.x >> 6);
    if (d >= n) return;
    int lane = threadIdx.x & 63;
    int half = lane >> 5;       // edge parity within the pair
    int cl = lane & 31;         // 4-channel chunk index
    const char* qvb = (const char*)QV;

    uint2 ku = *(const uint2*)((const unsigned short*)kb + (size_t)d * HDIM + 4 * cl);
    float k0 = bflo(ku.x), k1 = bfhi(ku.x), k2 = bflo(ku.y), k3 = bfhi(ku.y);
    float a0 = 0.f, a1 = 0.f, a2 = 0.f, a3 = 0.f;

#define EDGE4(u)                                                     \
    {                                                                \
        float g0 = k0 + bflo(u.x), g1 = k1 + bfhi(u.x);              \
        float g2 = k2 + bflo(u.y), g3 = k3 + bfhi(u.y);              \
        a0 += __fdividef(bflo(u.z), 1.f + __expf(-g0));              \
        a1 += __fdividef(bfhi(u.z), 1.f + __expf(-g1));              \
        a2 += __fdividef(bflo(u.w), 1.f + __expf(-g2));              \
        a3 += __fdividef(bfhi(u.w), 1.f + __expf(-g3));              \
    }

    int j = off[d] + half, s1 = off[d + 1];
    for (; j + 2 < s1; j += 4) {
        int sA = esrc[j], sB = esrc[j + 2];
        uint4 uA = *(const uint4*)(qvb + (size_t)sA * 512 + cl * 16);
        uint4 uB = *(const uint4*)(qvb + (size_t)sB * 512 + cl * 16);
        EDGE4(uA);
        EDGE4(uB);
    }
    if (j < s1) {
        int sA = esrc[j];
        uint4 uA = *(const uint4*)(qvb + (size_t)sA * 512 + cl * 16);
        EDGE4(uA);
    }
#undef EDGE4

    a0 += __shfl_xor(a0, 32);
    a1 += __shfl_xor(a1, 32);
    a2 += __shfl_xor(a2, 32);
    a3 += __shfl_xor(a3, 32);
    if (half == 0) {
        float4* sp = (float4*)(S + (size_t)d * HDIM) + cl;
        float4 o = *sp;
        o.x += a0; o.y += a1; o.z += a2; o.w += a3;
        *sp = o;
    }
}

// ---------------------------------------------------------------------------
// stats: per-channel sum / sumsq of S
// ---------------------------------------------------------------------------
__global__ void stats_kernel(const float* __restrict__ s,
                             float* __restrict__ stats, int n) {
    int c = threadIdx.x & 127, rh = threadIdx.x >> 7;
    int r0 = blockIdx.x * 128;
    int r1 = min(r0 + 128, n);
    float sum = 0.f, sq = 0.f;
    for (int r = r0 + rh; r < r1; r += 2) {
        float v = s[(size_t)r * HDIM + c];
        sum += v;
        sq = fmaf(v, v, sq);
    }
    __shared__ float ls[2][HDIM], lq[2][HDIM];
    ls[rh][c] = sum;
    lq[rh][c] = sq;
    __syncthreads();
    if (rh == 0) {
        atomicAdd(&stats[c], ls[0][c] + ls[1][c]);
        atomicAdd(&stats[HDIM + c], lq[0][c] + lq[1][c]);
    }
}

// ---------------------------------------------------------------------------
// head_bn: out = relu(bn(S)) @ head_w + head_b
// ---------------------------------------------------------------------------
__global__ void head_bn_kernel(const float* __restrict__ S,
                               const float* __restrict__ stats,
                               const float* __restrict__ gamma,
                               const float* __restrict__ beta,
                               const float* __restrict__ w,
                               const float* __restrict__ b,
                               float* __restrict__ out, int n) {
    __shared__ float hsm[8][HDIM];
    float invn = 1.f / (float)n;
    for (int i = threadIdx.x; i < 8 * HDIM; i += 256) {
        int r = i >> 7, c = i & 127;
        int node = blockIdx.x * 8 + r;
        float v = 0.f;
        if (node < n) {
            float mean = stats[c] * invn;
            float var = stats[128 + c] * invn - mean * mean;
            float sc = gamma[c] * rsqrtf(var + BN_EPS);
            float sh = beta[c] - mean * sc;
            v = fmaxf(fmaf(S[(size_t)node * HDIM + c], sc, sh), 0.f);
        }
        hsm[r][c] = v;
    }
    __syncthreads();
    int c = threadIdx.x & 31;
    int ng = threadIdx.x >> 5;
    int node = blockIdx.x * 8 + ng;
    if (node >= n) return;
    float acc = b[c];
#pragma unroll
    for (int k = 0; k < HDIM; ++k)
        acc = fmaf(hsm[ng][k], w[k * OCDIM + c], acc);
    out[(size_t)node * OCDIM + c] = acc;
}

// ---------------------------------------------------------------------------
extern "C" void kernel_launch(void* const* d_in, const int* in_sizes, int n_in,
                              void* d_out, int out_size, void* d_ws, size_t ws_size,
                              hipStream_t stream) {
    const float* x      = (const float*)d_in[0];
    const int*   ei     = (const int*)  d_in[1];
    const float* proj_w = (const float*)d_in[2];
    const float* proj_b = (const float*)d_in[3];
    const float* conv_w = (const float*)d_in[4];  // [3][4][128][128]
    const float* conv_b = (const float*)d_in[5];  // [3][4][128]
    const float* bn_g   = (const float*)d_in[6];
    const float* bn_b   = (const float*)d_in[7];
    const float* head_w = (const float*)d_in[8];
    const float* head_b = (const float*)d_in[9];
    float* out = (float*)d_out;

    int n = in_sizes[0] / ICDIM;   // 50000
    int e = in_sizes[1] / 2;       // 600000

    size_t nh = (size_t)n * HDIM;
    // S f32 | st[768] | h bf16 | K bf16 | QV u32 | Wt | Wp | ints
    size_t need = nh * 4 + 768 * 4 + nh * 2 + nh * 2 + nh * 4
                + (size_t)12 * HDIM * HDIM * 2 + (size_t)HDIM * ICDIM * 2
                + ((size_t)3 * n + (n + 1) + 256 + e) * 4;
    if (ws_size < need) return;

    float* S  = (float*)d_ws;
    float* st = S + nh;                         // 3 x (sum[128], sumsq[128])
    __hip_bfloat16* h = (__hip_bfloat16*)(st + 768);
    __hip_bfloat16* K = h + nh;
    unsigned int* QV = (unsigned int*)(K + nh); // [n][128] words (8B interleave)
    __hip_bfloat16* Wt = (__hip_bfloat16*)(QV + nh);     // [3][4][128o][128i]
    __hip_bfloat16* Wp = Wt + (size_t)12 * HDIM * HDIM;  // [128o][64i]

    int* deg    = (int*)(Wp + (size_t)HDIM * ICDIM);
    int* incl   = deg + n;
    int* off    = incl + n;                     // n+1
    int* cursor = off + n + 1;
    int* bsum   = cursor + n;                   // 256
    int* esrc   = bsum + 256;                   // e

    hipMemsetAsync(st, 0, 768 * sizeof(float), stream);
    hipMemsetAsync(deg, 0, (size_t)n * sizeof(int), stream);

    int gb_e = (e + 255) / 256;
    int gb_n = (n + 255) / 256;   // 196 <= 256

    wprep_kernel<<<13, 256, 0, stream>>>(conv_w, proj_w, Wt, Wp);
    proj_mfma_kernel<<<(n + NCH - 1) / NCH, 256, 0, stream>>>(x, Wp, proj_b, h, n);

    hist_kernel<<<gb_e, 256, 0, stream>>>(ei, deg, e);
    scan1_kernel<<<gb_n, 256, 0, stream>>>(deg, incl, bsum, n);
    scan23_kernel<<<gb_n, 256, 0, stream>>>(deg, incl, bsum, off, cursor, n, e, gb_n);
    scatter_kernel<<<gb_e, 256, 0, stream>>>(ei, cursor, esrc, e);

    int gm = (n + NCH - 1) / NCH;
    for (int l = 0; l < 3; ++l) {
        const float* Ssrc = (l == 0) ? nullptr : S;
        const float* stp  = (l == 0) ? st : st + (size_t)(l - 1) * 256;
        const float* gma  = (l == 0) ? bn_g : bn_g + (size_t)(l - 1) * HDIM;
        const float* bta  = (l == 0) ? bn_b : bn_b + (size_t)(l - 1) * HDIM;
        gemm4_fused_kernel<<<gm, 1024, 0, stream>>>(
            h, Ssrc, stp, gma, bta,
            Wt + (size_t)l * 4 * HDIM * HDIM, conv_b + (size_t)l * 4 * HDIM,
            K, QV, S, n);
        agg_kernel<<<(n + 3) / 4, 256, 0, stream>>>(off, esrc, K, QV, S, n);
        stats_kernel<<<(n + 127) / 128, 256, 0, stream>>>(S, st + l * 256, n);
    }

    head_bn_kernel<<<(n + 7) / 8, 256, 0, stream>>>(
        S, st + 2 * 256, bn_g + 2 * HDIM, bn_b + 2 * HDIM, head_w, head_b, out, n);
}